// Round 1
// baseline (2069.569 us; speedup 1.0000x reference)
//
#include <hip/hip_runtime.h>
#include <math.h>

namespace {

constexpr float ALPHA = 0.3f;
constexpr int B  = 16;
constexpr int N  = 1024;
constexpr int H  = 256;
constexpr int H2 = 512;
constexpr int NT = B * N;        // 16384 total nodes
constexpr int NE = N - 1;        // 1023 MST edges per batch
constexpr int CAP = 32;          // adjacency capacity per node (MST degree << 32)

// ---------------- row squared-norms: n2[row] = sum_k x[row][k]^2 ----------------
__global__ void n2_kernel(const float* __restrict__ x, float* __restrict__ n2) {
  int wave = threadIdx.x >> 6, lane = threadIdx.x & 63;
  int row  = blockIdx.x * 4 + wave;                 // 4096 blocks * 4 waves = 16384 rows
  float4 v = *(const float4*)(x + (size_t)row * H + lane * 4);
  float s  = v.x * v.x + v.y * v.y + v.z * v.z + v.w * v.w;
  #pragma unroll
  for (int off = 32; off; off >>= 1) s += __shfl_xor(s, off);
  if (lane == 0) n2[row] = s;
}

// ---------------- distance matrix: D[b][i][j] = sqrt(max(n2i+n2j-2*dot,0)) ------
// 64x64 output tile per 256-thread block, K=256 in chunks of 32, k-major LDS tiles.
__global__ __launch_bounds__(256) void dist_kernel(const float* __restrict__ x,
    const float* __restrict__ n2, float* __restrict__ dist) {
  __shared__ float As[32][64], Bs[32][64];
  const int bb = blockIdx.z;
  const int i0 = blockIdx.y * 64, j0 = blockIdx.x * 64;
  const int t = threadIdx.x, tx = t & 15, ty = t >> 4;
  const float* xb = x + (size_t)bb * N * H;
  float acc[4][4] = {};
  for (int kc = 0; kc < H; kc += 32) {
    #pragma unroll
    for (int u = 0; u < 2; ++u) {
      int q = t + u * 256;
      int row = q >> 3, kf = (q & 7) * 4;           // 8 float4 per 32-wide k-slice
      float4 a = *(const float4*)(xb + (size_t)(i0 + row) * H + kc + kf);
      As[kf + 0][row] = a.x; As[kf + 1][row] = a.y;
      As[kf + 2][row] = a.z; As[kf + 3][row] = a.w;
      float4 bv = *(const float4*)(xb + (size_t)(j0 + row) * H + kc + kf);
      Bs[kf + 0][row] = bv.x; Bs[kf + 1][row] = bv.y;
      Bs[kf + 2][row] = bv.z; Bs[kf + 3][row] = bv.w;
    }
    __syncthreads();
    #pragma unroll
    for (int kk = 0; kk < 32; ++kk) {
      float4 a  = *(const float4*)&As[kk][ty * 4];
      float4 bv = *(const float4*)&Bs[kk][tx * 4];
      float ar[4] = {a.x, a.y, a.z, a.w}, br[4] = {bv.x, bv.y, bv.z, bv.w};
      #pragma unroll
      for (int r = 0; r < 4; ++r)
        #pragma unroll
        for (int c = 0; c < 4; ++c) acc[r][c] += ar[r] * br[c];
    }
    __syncthreads();
  }
  float n2i[4], n2j[4];
  #pragma unroll
  for (int r = 0; r < 4; ++r) n2i[r] = n2[bb * N + i0 + ty * 4 + r];
  #pragma unroll
  for (int c = 0; c < 4; ++c) n2j[c] = n2[bb * N + j0 + tx * 4 + c];
  #pragma unroll
  for (int r = 0; r < 4; ++r) {
    float o[4];
    #pragma unroll
    for (int c = 0; c < 4; ++c) {
      float d2 = (n2i[r] + n2j[c]) - 2.0f * acc[r][c];   // match reference formula
      o[c] = sqrtf(fmaxf(d2, 0.0f));
    }
    *(float4*)(dist + ((size_t)bb * N + i0 + ty * 4 + r) * N + j0 + tx * 4) =
        make_float4(o[0], o[1], o[2], o[3]);
  }
}

// ---------------- Prim MST: 1 wave per batch, all state in registers ------------
// Node j owned by lane (j>>4), slot (j&15). Tie-break = lowest node id (jnp.argmin).
__global__ void prim_kernel(const float* __restrict__ dist,
    int* __restrict__ ep, int* __restrict__ ev, float* __restrict__ ewt) {
  const int b = blockIdx.x, lane = threadIdx.x;     // 64 threads
  const float* Db = dist + (size_t)b * N * N;
  float mind[16]; int par[16]; unsigned intree = 0;
  #pragma unroll
  for (int u = 0; u < 4; ++u) {                     // mind = dist[0] row
    float4 v = ((const float4*)Db)[lane * 4 + u];
    mind[4*u+0] = v.x; mind[4*u+1] = v.y; mind[4*u+2] = v.z; mind[4*u+3] = v.w;
  }
  #pragma unroll
  for (int s = 0; s < 16; ++s) par[s] = 0;
  if (lane == 0) intree = 1u;                        // node 0 in tree
  for (int k = 0; k < NE; ++k) {
    // local argmin over this lane's 16 slots (ascending node id keeps first-min)
    float bw = 1e30f; int bj = 0x7fffffff; int bp = 0;
    #pragma unroll
    for (int s = 0; s < 16; ++s) {
      float w = ((intree >> s) & 1) ? 1e30f : mind[s];
      if (w < bw) { bw = w; bj = lane * 16 + s; bp = par[s]; }
    }
    // wave butterfly argmin on (w, j, p); all lanes converge
    #pragma unroll
    for (int off = 32; off; off >>= 1) {
      float w2 = __shfl_xor(bw, off);
      int   j2 = __shfl_xor(bj, off);
      int   p2 = __shfl_xor(bp, off);
      if (w2 < bw || (w2 == bw && j2 < bj)) { bw = w2; bj = j2; bp = p2; }
    }
    if (lane == 0) { ep[b * NE + k] = bp; ev[b * NE + k] = bj; ewt[b * NE + k] = bw; }
    if (lane == (bj >> 4)) intree |= 1u << (bj & 15);
    // update mind/par from row bj
    const float* rowp = Db + (size_t)bj * N;
    float rv[16];
    #pragma unroll
    for (int u = 0; u < 4; ++u) {
      float4 v = ((const float4*)rowp)[lane * 4 + u];
      rv[4*u+0] = v.x; rv[4*u+1] = v.y; rv[4*u+2] = v.z; rv[4*u+3] = v.w;
    }
    #pragma unroll
    for (int s = 0; s < 16; ++s) {
      if (!((intree >> s) & 1) && rv[s] < mind[s]) { mind[s] = rv[s]; par[s] = bj; }
    }
  }
}

// ---------------- adjacency + deg^-1/2 (deterministic, no atomics) --------------
__global__ void adj_kernel(const int* __restrict__ ep, const int* __restrict__ ev,
    const float* __restrict__ ewt, int* __restrict__ adjI, float* __restrict__ adjW,
    int* __restrict__ cnt, float* __restrict__ dinv) {
  int i = blockIdx.x * 256 + threadIdx.x;            // global node 0..16383
  int b = i >> 10, loc = i & 1023;
  const int* epb = ep + b * NE;
  const int* evb = ev + b * NE;
  const float* ewb = ewt + b * NE;
  int c = 0; float wsum = 0.0f;
  for (int k = 0; k < NE; ++k) {
    int p = epb[k], v = evb[k];
    if (p == loc || v == loc) {
      float w = ewb[k];
      wsum += w;
      int nb = (p == loc) ? v : p;
      if (c < CAP) { adjI[i * CAP + c] = (b << 10) + nb; adjW[i * CAP + c] = w; }
      ++c;
    }
  }
  cnt[i]  = c < CAP ? c : CAP;
  dinv[i] = 1.0f / sqrtf(wsum + 1.0f);               // + self-loop weight 1
}

// ---------------- SSG propagation: h = alpha*x + (1-alpha)*A_hat x --------------
// One wave per node; HH/64 floats per lane.
template <int HH>
__global__ void prop_kernel(const float* __restrict__ x, const int* __restrict__ adjI,
    const float* __restrict__ adjW, const int* __restrict__ cnt,
    const float* __restrict__ dinv, float* __restrict__ h) {
  constexpr int U = HH / 256;                        // float4 chunks per lane (1 or 2)
  int wave = threadIdx.x >> 6, lane = threadIdx.x & 63;
  int i = blockIdx.x * 4 + wave;
  float dv = dinv[i];
  int c = cnt[i];
  float selfc = ALPHA + (1.0f - ALPHA) * dv * dv;    // alpha + (1-alpha)*self-loop
  float4 acc[U];
  const float* xi = x + (size_t)i * HH + lane * 4;
  #pragma unroll
  for (int u = 0; u < U; ++u) {
    float4 v = *(const float4*)(xi + u * 256);
    acc[u].x = selfc * v.x; acc[u].y = selfc * v.y;
    acc[u].z = selfc * v.z; acc[u].w = selfc * v.w;
  }
  for (int e = 0; e < c; ++e) {
    int j   = adjI[i * CAP + e];
    float w = adjW[i * CAP + e];
    float coef = (1.0f - ALPHA) * dv * (w * dinv[j]);
    const float* xj = x + (size_t)j * HH + lane * 4;
    #pragma unroll
    for (int u = 0; u < U; ++u) {
      float4 v = *(const float4*)(xj + u * 256);
      acc[u].x += coef * v.x; acc[u].y += coef * v.y;
      acc[u].z += coef * v.z; acc[u].w += coef * v.w;
    }
  }
  float* ho = h + (size_t)i * HH + lane * 4;
  #pragma unroll
  for (int u = 0; u < U; ++u) *(float4*)(ho + u * 256) = acc[u];
}

// ---------------- fused GEMM + bias + tanh: C[M,512] = tanh(A[M,K] @ W[K,512] + b)
template <int K>
__global__ __launch_bounds__(256) void gemm_tanh_kernel(const float* __restrict__ A,
    const float* __restrict__ W, const float* __restrict__ bias, float* __restrict__ C) {
  __shared__ float As[32][64], Bs[32][64];
  const int m0 = blockIdx.x * 64, n0 = blockIdx.y * 64;
  const int t = threadIdx.x, tx = t & 15, ty = t >> 4;
  float acc[4][4] = {};
  for (int kc = 0; kc < K; kc += 32) {
    #pragma unroll
    for (int u = 0; u < 2; ++u) {
      int q = t + u * 256;
      int rowA = q >> 3, kf = (q & 7) * 4;
      float4 a = *(const float4*)(A + (size_t)(m0 + rowA) * K + kc + kf);
      As[kf + 0][rowA] = a.x; As[kf + 1][rowA] = a.y;
      As[kf + 2][rowA] = a.z; As[kf + 3][rowA] = a.w;
      int rowB = q >> 4, cf = (q & 15) * 4;
      *(float4*)&Bs[rowB][cf] = *(const float4*)(W + (size_t)(kc + rowB) * H2 + n0 + cf);
    }
    __syncthreads();
    #pragma unroll
    for (int kk = 0; kk < 32; ++kk) {
      float4 a  = *(const float4*)&As[kk][ty * 4];
      float4 bv = *(const float4*)&Bs[kk][tx * 4];
      float ar[4] = {a.x, a.y, a.z, a.w}, br[4] = {bv.x, bv.y, bv.z, bv.w};
      #pragma unroll
      for (int r = 0; r < 4; ++r)
        #pragma unroll
        for (int c = 0; c < 4; ++c) acc[r][c] += ar[r] * br[c];
    }
    __syncthreads();
  }
  #pragma unroll
  for (int r = 0; r < 4; ++r) {
    float o[4];
    #pragma unroll
    for (int c = 0; c < 4; ++c) o[c] = tanhf(acc[r][c] + bias[n0 + tx * 4 + c]);
    *(float4*)(C + (size_t)(m0 + ty * 4 + r) * H2 + n0 + tx * 4) =
        make_float4(o[0], o[1], o[2], o[3]);
  }
}

// ---------------- mean pool over N nodes per graph ------------------------------
__global__ void pool_kernel(const float* __restrict__ x, float* __restrict__ pooled) {
  int b = blockIdx.x;
  int c = blockIdx.y * 256 + threadIdx.x;            // channel 0..511
  const float* xb = x + ((size_t)b << 10) * H2 + c;
  float s = 0.0f;
  for (int i = 0; i < N; ++i) s += xb[(size_t)i * H2];
  pooled[b * H2 + c] = s * (1.0f / N);
}

// ---------------- dense head: tanh(pooled@Wd+bd) @ Wo + bo ----------------------
__global__ void head_kernel(const float* __restrict__ pooled, const float* __restrict__ Wd,
    const float* __restrict__ bd, const float* __restrict__ Wo, const float* __restrict__ bo,
    float* __restrict__ out) {
  __shared__ float sp[512], sh[256];
  int b = blockIdx.x, t = threadIdx.x;
  sp[t] = pooled[b * H2 + t];
  sp[t + 256] = pooled[b * H2 + t + 256];
  __syncthreads();
  float acc = bd[t];
  for (int c2 = 0; c2 < 512; ++c2) acc += sp[c2] * Wd[c2 * 256 + t];
  sh[t] = tanhf(acc);
  __syncthreads();
  if (t < 8) {
    float o = bo[t];
    for (int j = 0; j < 256; ++j) o += sh[j] * Wo[j * 8 + t];
    out[b * 8 + t] = o;
  }
}

}  // namespace

extern "C" void kernel_launch(void* const* d_in, const int* in_sizes, int n_in,
                              void* d_out, int out_size, void* d_ws, size_t ws_size,
                              hipStream_t stream) {
  const float* feat = (const float*)d_in[0];
  const float* W1 = (const float*)d_in[1];
  const float* b1 = (const float*)d_in[2];
  const float* W2 = (const float*)d_in[3];
  const float* b2 = (const float*)d_in[4];
  const float* W3 = (const float*)d_in[5];
  const float* b3 = (const float*)d_in[6];
  const float* Wd = (const float*)d_in[7];
  const float* bd = (const float*)d_in[8];
  const float* Wo = (const float*)d_in[9];
  const float* bo = (const float*)d_in[10];
  float* out = (float*)d_out;
  char* ws = (char*)d_ws;

  // Workspace layout (~101 MB):
  //  [0,   64MB)  dist matrix; after Prim, reused as x-buffer (32MB)
  //  [64MB,96MB)  h buffer
  //  [96MB, ...)  misc: edges, adjacency, norms, pooled
  float* dist = (float*)(ws);
  float* xcur = (float*)(ws);
  float* hbuf = (float*)(ws + ((size_t)64 << 20));
  char* misc  = ws + ((size_t)96 << 20);
  int*   ep     = (int*)(misc);
  int*   ev     = (int*)(misc + 65536);
  float* ewt    = (float*)(misc + 131072);
  int*   cnt    = (int*)(misc + 196608);
  float* dinv   = (float*)(misc + 262144);
  int*   adjI   = (int*)(misc + 327680);
  float* adjW   = (float*)(misc + 327680 + 2097152);
  float* n2     = (float*)(misc + 327680 + 2 * 2097152);
  float* pooled = (float*)(misc + 327680 + 2 * 2097152 + 65536);

  n2_kernel<<<NT / 4, 256, 0, stream>>>(feat, n2);
  dist_kernel<<<dim3(16, 16, 16), 256, 0, stream>>>(feat, n2, dist);
  prim_kernel<<<B, 64, 0, stream>>>(dist, ep, ev, ewt);
  adj_kernel<<<NT / 256, 256, 0, stream>>>(ep, ev, ewt, adjI, adjW, cnt, dinv);

  // Layer 1: H=256 -> 512
  prop_kernel<256><<<NT / 4, 256, 0, stream>>>(feat, adjI, adjW, cnt, dinv, hbuf);
  gemm_tanh_kernel<256><<<dim3(NT / 64, H2 / 64), 256, 0, stream>>>(hbuf, W1, b1, xcur);
  // Layer 2
  prop_kernel<512><<<NT / 4, 256, 0, stream>>>(xcur, adjI, adjW, cnt, dinv, hbuf);
  gemm_tanh_kernel<512><<<dim3(NT / 64, H2 / 64), 256, 0, stream>>>(hbuf, W2, b2, xcur);
  // Layer 3
  prop_kernel<512><<<NT / 4, 256, 0, stream>>>(xcur, adjI, adjW, cnt, dinv, hbuf);
  gemm_tanh_kernel<512><<<dim3(NT / 64, H2 / 64), 256, 0, stream>>>(hbuf, W3, b3, xcur);

  pool_kernel<<<dim3(B, H2 / 256), 256, 0, stream>>>(xcur, pooled);
  head_kernel<<<B, 256, 0, stream>>>(pooled, Wd, bd, Wo, bo, out);
}

// Round 2
// 1917.414 us; speedup vs baseline: 1.0794x; 1.0794x over previous
//
#include <hip/hip_runtime.h>
#include <math.h>

namespace {

constexpr float ALPHA = 0.3f;
constexpr int B  = 16;
constexpr int N  = 1024;
constexpr int H  = 256;
constexpr int H2 = 512;
constexpr int NT = B * N;        // 16384 total nodes
constexpr int NE = N - 1;        // 1023 MST edges per batch
constexpr int CAP = 32;          // adjacency capacity per node (MST degree << 32)

// ---------------- row squared-norms: n2[row] = sum_k x[row][k]^2 ----------------
__global__ void n2_kernel(const float* __restrict__ x, float* __restrict__ n2) {
  int wave = threadIdx.x >> 6, lane = threadIdx.x & 63;
  int row  = blockIdx.x * 4 + wave;                 // 4096 blocks * 4 waves = 16384 rows
  float4 v = *(const float4*)(x + (size_t)row * H + lane * 4);
  float s  = v.x * v.x + v.y * v.y + v.z * v.z + v.w * v.w;
  #pragma unroll
  for (int off = 32; off; off >>= 1) s += __shfl_xor(s, off);
  if (lane == 0) n2[row] = s;
}

// ---------------- distance matrix: D[b][i][j] = sqrt(max(n2i+n2j-2*dot,0)) ------
// 64x64 output tile per 256-thread block, K=256 in chunks of 32, k-major LDS tiles.
__global__ __launch_bounds__(256) void dist_kernel(const float* __restrict__ x,
    const float* __restrict__ n2, float* __restrict__ dist) {
  __shared__ float As[32][64], Bs[32][64];
  const int bb = blockIdx.z;
  const int i0 = blockIdx.y * 64, j0 = blockIdx.x * 64;
  const int t = threadIdx.x, tx = t & 15, ty = t >> 4;
  const float* xb = x + (size_t)bb * N * H;
  float acc[4][4] = {};
  for (int kc = 0; kc < H; kc += 32) {
    #pragma unroll
    for (int u = 0; u < 2; ++u) {
      int q = t + u * 256;
      int row = q >> 3, kf = (q & 7) * 4;           // 8 float4 per 32-wide k-slice
      float4 a = *(const float4*)(xb + (size_t)(i0 + row) * H + kc + kf);
      As[kf + 0][row] = a.x; As[kf + 1][row] = a.y;
      As[kf + 2][row] = a.z; As[kf + 3][row] = a.w;
      float4 bv = *(const float4*)(xb + (size_t)(j0 + row) * H + kc + kf);
      Bs[kf + 0][row] = bv.x; Bs[kf + 1][row] = bv.y;
      Bs[kf + 2][row] = bv.z; Bs[kf + 3][row] = bv.w;
    }
    __syncthreads();
    #pragma unroll
    for (int kk = 0; kk < 32; ++kk) {
      float4 a  = *(const float4*)&As[kk][ty * 4];
      float4 bv = *(const float4*)&Bs[kk][tx * 4];
      float ar[4] = {a.x, a.y, a.z, a.w}, br[4] = {bv.x, bv.y, bv.z, bv.w};
      #pragma unroll
      for (int r = 0; r < 4; ++r)
        #pragma unroll
        for (int c = 0; c < 4; ++c) acc[r][c] += ar[r] * br[c];
    }
    __syncthreads();
  }
  float n2i[4], n2j[4];
  #pragma unroll
  for (int r = 0; r < 4; ++r) n2i[r] = n2[bb * N + i0 + ty * 4 + r];
  #pragma unroll
  for (int c = 0; c < 4; ++c) n2j[c] = n2[bb * N + j0 + tx * 4 + c];
  #pragma unroll
  for (int r = 0; r < 4; ++r) {
    float o[4];
    #pragma unroll
    for (int c = 0; c < 4; ++c) {
      float d2 = (n2i[r] + n2j[c]) - 2.0f * acc[r][c];   // match reference formula
      o[c] = sqrtf(fmaxf(d2, 0.0f));
    }
    *(float4*)(dist + ((size_t)bb * N + i0 + ty * 4 + r) * N + j0 + tx * 4) =
        make_float4(o[0], o[1], o[2], o[3]);
  }
}

// ---------------- Prim MST: 1 wave per batch, u64-key argmin, parent in LDS -----
// Node j owned by lane (j>>4), slot (j&15). Key = (float_bits(w)<<32)|j so u64 min
// == (min weight, lowest index on tie) == jnp.argmin semantics. Parent lives in
// LDS (owner-lane writes only), keeping the butterfly to a single u64 value.
__global__ void prim_kernel(const float* __restrict__ dist,
    int* __restrict__ ep, int* __restrict__ ev, float* __restrict__ ewt) {
  __shared__ int par[N];                             // 4KB, parent per node
  const int b = blockIdx.x, lane = threadIdx.x;      // 64 threads
  const float* Db = dist + (size_t)b * N * N;
  const int jbase = lane * 16;
  int* epb = ep + b * NE;
  int* evb = ev + b * NE;
  float* ewb = ewt + b * NE;

  #pragma unroll
  for (int u = 0; u < 16; ++u) par[u * 64 + lane] = 0;

  float mind[16];
  #pragma unroll
  for (int u = 0; u < 4; ++u) {                      // mind = dist[0] row
    float4 v = ((const float4*)Db)[lane * 4 + u];
    mind[4*u+0] = v.x; mind[4*u+1] = v.y; mind[4*u+2] = v.z; mind[4*u+3] = v.w;
  }
  unsigned intree = (lane == 0) ? 1u : 0u;           // node 0 in tree

  for (int k = 0; k < NE; ++k) {
    // --- selection: u64 keys, in-tree slots masked to max ---
    unsigned long long kv[16];
    #pragma unroll
    for (int s = 0; s < 16; ++s) {
      unsigned long long key =
          ((unsigned long long)__float_as_uint(mind[s]) << 32) | (unsigned)(jbase + s);
      kv[s] = ((intree >> s) & 1u) ? ~0ull : key;
    }
    #pragma unroll
    for (int step = 8; step; step >>= 1)
      #pragma unroll
      for (int s = 0; s < step; ++s)
        kv[s] = kv[s + step] < kv[s] ? kv[s + step] : kv[s];
    unsigned long long best = kv[0];
    #pragma unroll
    for (int off = 32; off; off >>= 1) {
      unsigned long long o = __shfl_xor(best, off);
      best = o < best ? o : best;
    }
    const int gj = (int)(unsigned)(best & 0xFFFFFFFFu);
    const float gw = __uint_as_float((unsigned)(best >> 32));

    // --- issue row load ASAP (bookkeeping below hides in its shadow) ---
    const float* rowp = Db + (size_t)gj * N;
    float4 r0 = ((const float4*)rowp)[lane * 4 + 0];
    float4 r1 = ((const float4*)rowp)[lane * 4 + 1];
    float4 r2 = ((const float4*)rowp)[lane * 4 + 2];
    float4 r3 = ((const float4*)rowp)[lane * 4 + 3];

    if (lane == 0) { epb[k] = par[gj]; evb[k] = gj; ewb[k] = gw; }
    if (lane == (gj >> 4)) intree |= 1u << (gj & 15);

    // --- update mind/parent from row gj ---
    float rv[16];
    rv[0]=r0.x; rv[1]=r0.y; rv[2]=r0.z; rv[3]=r0.w;
    rv[4]=r1.x; rv[5]=r1.y; rv[6]=r1.z; rv[7]=r1.w;
    rv[8]=r2.x; rv[9]=r2.y; rv[10]=r2.z; rv[11]=r2.w;
    rv[12]=r3.x; rv[13]=r3.y; rv[14]=r3.z; rv[15]=r3.w;
    #pragma unroll
    for (int s = 0; s < 16; ++s) {
      bool upd = rv[s] < mind[s];                    // strict <, matches reference
      if (upd) par[jbase + s] = gj;                  // owner-lane only, no conflict
      mind[s] = upd ? rv[s] : mind[s];
    }
  }
}

// ---------------- adjacency + deg^-1/2 (deterministic, no atomics) --------------
__global__ void adj_kernel(const int* __restrict__ ep, const int* __restrict__ ev,
    const float* __restrict__ ewt, int* __restrict__ adjI, float* __restrict__ adjW,
    int* __restrict__ cnt, float* __restrict__ dinv) {
  int i = blockIdx.x * 256 + threadIdx.x;            // global node 0..16383
  int b = i >> 10, loc = i & 1023;
  const int* epb = ep + b * NE;
  const int* evb = ev + b * NE;
  const float* ewb = ewt + b * NE;
  int c = 0; float wsum = 0.0f;
  for (int k = 0; k < NE; ++k) {
    int p = epb[k], v = evb[k];
    if (p == loc || v == loc) {
      float w = ewb[k];
      wsum += w;
      int nb = (p == loc) ? v : p;
      if (c < CAP) { adjI[i * CAP + c] = (b << 10) + nb; adjW[i * CAP + c] = w; }
      ++c;
    }
  }
  cnt[i]  = c < CAP ? c : CAP;
  dinv[i] = 1.0f / sqrtf(wsum + 1.0f);               // + self-loop weight 1
}

// ---------------- SSG propagation: h = alpha*x + (1-alpha)*A_hat x --------------
// One wave per node; HH/64 floats per lane.
template <int HH>
__global__ void prop_kernel(const float* __restrict__ x, const int* __restrict__ adjI,
    const float* __restrict__ adjW, const int* __restrict__ cnt,
    const float* __restrict__ dinv, float* __restrict__ h) {
  constexpr int U = HH / 256;                        // float4 chunks per lane (1 or 2)
  int wave = threadIdx.x >> 6, lane = threadIdx.x & 63;
  int i = blockIdx.x * 4 + wave;
  float dv = dinv[i];
  int c = cnt[i];
  float selfc = ALPHA + (1.0f - ALPHA) * dv * dv;    // alpha + (1-alpha)*self-loop
  float4 acc[U];
  const float* xi = x + (size_t)i * HH + lane * 4;
  #pragma unroll
  for (int u = 0; u < U; ++u) {
    float4 v = *(const float4*)(xi + u * 256);
    acc[u].x = selfc * v.x; acc[u].y = selfc * v.y;
    acc[u].z = selfc * v.z; acc[u].w = selfc * v.w;
  }
  for (int e = 0; e < c; ++e) {
    int j   = adjI[i * CAP + e];
    float w = adjW[i * CAP + e];
    float coef = (1.0f - ALPHA) * dv * (w * dinv[j]);
    const float* xj = x + (size_t)j * HH + lane * 4;
    #pragma unroll
    for (int u = 0; u < U; ++u) {
      float4 v = *(const float4*)(xj + u * 256);
      acc[u].x += coef * v.x; acc[u].y += coef * v.y;
      acc[u].z += coef * v.z; acc[u].w += coef * v.w;
    }
  }
  float* ho = h + (size_t)i * HH + lane * 4;
  #pragma unroll
  for (int u = 0; u < U; ++u) *(float4*)(ho + u * 256) = acc[u];
}

// ---------------- fused GEMM + bias + tanh: C[M,512] = tanh(A[M,K] @ W[K,512] + b)
template <int K>
__global__ __launch_bounds__(256) void gemm_tanh_kernel(const float* __restrict__ A,
    const float* __restrict__ W, const float* __restrict__ bias, float* __restrict__ C) {
  __shared__ float As[32][64], Bs[32][64];
  const int m0 = blockIdx.x * 64, n0 = blockIdx.y * 64;
  const int t = threadIdx.x, tx = t & 15, ty = t >> 4;
  float acc[4][4] = {};
  for (int kc = 0; kc < K; kc += 32) {
    #pragma unroll
    for (int u = 0; u < 2; ++u) {
      int q = t + u * 256;
      int rowA = q >> 3, kf = (q & 7) * 4;
      float4 a = *(const float4*)(A + (size_t)(m0 + rowA) * K + kc + kf);
      As[kf + 0][rowA] = a.x; As[kf + 1][rowA] = a.y;
      As[kf + 2][rowA] = a.z; As[kf + 3][rowA] = a.w;
      int rowB = q >> 4, cf = (q & 15) * 4;
      *(float4*)&Bs[rowB][cf] = *(const float4*)(W + (size_t)(kc + rowB) * H2 + n0 + cf);
    }
    __syncthreads();
    #pragma unroll
    for (int kk = 0; kk < 32; ++kk) {
      float4 a  = *(const float4*)&As[kk][ty * 4];
      float4 bv = *(const float4*)&Bs[kk][tx * 4];
      float ar[4] = {a.x, a.y, a.z, a.w}, br[4] = {bv.x, bv.y, bv.z, bv.w};
      #pragma unroll
      for (int r = 0; r < 4; ++r)
        #pragma unroll
        for (int c = 0; c < 4; ++c) acc[r][c] += ar[r] * br[c];
    }
    __syncthreads();
  }
  #pragma unroll
  for (int r = 0; r < 4; ++r) {
    float o[4];
    #pragma unroll
    for (int c = 0; c < 4; ++c) o[c] = tanhf(acc[r][c] + bias[n0 + tx * 4 + c]);
    *(float4*)(C + (size_t)(m0 + ty * 4 + r) * H2 + n0 + tx * 4) =
        make_float4(o[0], o[1], o[2], o[3]);
  }
}

// ---------------- mean pool over N nodes per graph ------------------------------
__global__ void pool_kernel(const float* __restrict__ x, float* __restrict__ pooled) {
  int b = blockIdx.x;
  int c = blockIdx.y * 256 + threadIdx.x;            // channel 0..511
  const float* xb = x + ((size_t)b << 10) * H2 + c;
  float s = 0.0f;
  for (int i = 0; i < N; ++i) s += xb[(size_t)i * H2];
  pooled[b * H2 + c] = s * (1.0f / N);
}

// ---------------- dense head: tanh(pooled@Wd+bd) @ Wo + bo ----------------------
__global__ void head_kernel(const float* __restrict__ pooled, const float* __restrict__ Wd,
    const float* __restrict__ bd, const float* __restrict__ Wo, const float* __restrict__ bo,
    float* __restrict__ out) {
  __shared__ float sp[512], sh[256];
  int b = blockIdx.x, t = threadIdx.x;
  sp[t] = pooled[b * H2 + t];
  sp[t + 256] = pooled[b * H2 + t + 256];
  __syncthreads();
  float acc = bd[t];
  for (int c2 = 0; c2 < 512; ++c2) acc += sp[c2] * Wd[c2 * 256 + t];
  sh[t] = tanhf(acc);
  __syncthreads();
  if (t < 8) {
    float o = bo[t];
    for (int j = 0; j < 256; ++j) o += sh[j] * Wo[j * 8 + t];
    out[b * 8 + t] = o;
  }
}

}  // namespace

extern "C" void kernel_launch(void* const* d_in, const int* in_sizes, int n_in,
                              void* d_out, int out_size, void* d_ws, size_t ws_size,
                              hipStream_t stream) {
  const float* feat = (const float*)d_in[0];
  const float* W1 = (const float*)d_in[1];
  const float* b1 = (const float*)d_in[2];
  const float* W2 = (const float*)d_in[3];
  const float* b2 = (const float*)d_in[4];
  const float* W3 = (const float*)d_in[5];
  const float* b3 = (const float*)d_in[6];
  const float* Wd = (const float*)d_in[7];
  const float* bd = (const float*)d_in[8];
  const float* Wo = (const float*)d_in[9];
  const float* bo = (const float*)d_in[10];
  float* out = (float*)d_out;
  char* ws = (char*)d_ws;

  // Workspace layout (~101 MB):
  //  [0,   64MB)  dist matrix; after Prim, reused as x-buffer (32MB)
  //  [64MB,96MB)  h buffer
  //  [96MB, ...)  misc: edges, adjacency, norms, pooled
  float* dist = (float*)(ws);
  float* xcur = (float*)(ws);
  float* hbuf = (float*)(ws + ((size_t)64 << 20));
  char* misc  = ws + ((size_t)96 << 20);
  int*   ep     = (int*)(misc);
  int*   ev     = (int*)(misc + 65536);
  float* ewt    = (float*)(misc + 131072);
  int*   cnt    = (int*)(misc + 196608);
  float* dinv   = (float*)(misc + 262144);
  int*   adjI   = (int*)(misc + 327680);
  float* adjW   = (float*)(misc + 327680 + 2097152);
  float* n2     = (float*)(misc + 327680 + 2 * 2097152);
  float* pooled = (float*)(misc + 327680 + 2 * 2097152 + 65536);

  n2_kernel<<<NT / 4, 256, 0, stream>>>(feat, n2);
  dist_kernel<<<dim3(16, 16, 16), 256, 0, stream>>>(feat, n2, dist);
  prim_kernel<<<B, 64, 0, stream>>>(dist, ep, ev, ewt);
  adj_kernel<<<NT / 256, 256, 0, stream>>>(ep, ev, ewt, adjI, adjW, cnt, dinv);

  // Layer 1: H=256 -> 512
  prop_kernel<256><<<NT / 4, 256, 0, stream>>>(feat, adjI, adjW, cnt, dinv, hbuf);
  gemm_tanh_kernel<256><<<dim3(NT / 64, H2 / 64), 256, 0, stream>>>(hbuf, W1, b1, xcur);
  // Layer 2
  prop_kernel<512><<<NT / 4, 256, 0, stream>>>(xcur, adjI, adjW, cnt, dinv, hbuf);
  gemm_tanh_kernel<512><<<dim3(NT / 64, H2 / 64), 256, 0, stream>>>(hbuf, W2, b2, xcur);
  // Layer 3
  prop_kernel<512><<<NT / 4, 256, 0, stream>>>(xcur, adjI, adjW, cnt, dinv, hbuf);
  gemm_tanh_kernel<512><<<dim3(NT / 64, H2 / 64), 256, 0, stream>>>(hbuf, W3, b3, xcur);

  pool_kernel<<<dim3(B, H2 / 256), 256, 0, stream>>>(xcur, pooled);
  head_kernel<<<B, 256, 0, stream>>>(pooled, Wd, bd, Wo, bo, out);
}

// Round 3
// 1729.785 us; speedup vs baseline: 1.1964x; 1.1085x over previous
//
#include <hip/hip_runtime.h>
#include <math.h>

namespace {

constexpr float ALPHA = 0.3f;
constexpr int B  = 16;
constexpr int N  = 1024;
constexpr int H  = 256;
constexpr int H2 = 512;
constexpr int NT = B * N;        // 16384 total nodes
constexpr int NE = N - 1;        // 1023 MST edges per batch
constexpr int CAP = 32;          // adjacency capacity per node (MST degree << 32)

__device__ __forceinline__ unsigned umin32(unsigned a, unsigned b) { return a < b ? a : b; }

// ---------------- row squared-norms: n2[row] = sum_k x[row][k]^2 ----------------
__global__ void n2_kernel(const float* __restrict__ x, float* __restrict__ n2) {
  int wave = threadIdx.x >> 6, lane = threadIdx.x & 63;
  int row  = blockIdx.x * 4 + wave;
  float4 v = *(const float4*)(x + (size_t)row * H + lane * 4);
  float s  = v.x * v.x + v.y * v.y + v.z * v.z + v.w * v.w;
  #pragma unroll
  for (int off = 32; off; off >>= 1) s += __shfl_xor(s, off);
  if (lane == 0) n2[row] = s;
}

// ---------------- distance matrix: 128x128 tile, 8x8 per thread -----------------
__global__ __launch_bounds__(256) void dist_kernel(const float* __restrict__ x,
    const float* __restrict__ n2, float* __restrict__ dist) {
  __shared__ float As[16][132], Bs[16][132];
  const int bb = blockIdx.z;
  const int i0 = blockIdx.y * 128, j0 = blockIdx.x * 128;
  const int t = threadIdx.x, tx = t & 15, ty = t >> 4;
  const float* xb = x + (size_t)bb * N * H;
  float acc[8][8] = {};
  for (int kc = 0; kc < H; kc += 16) {
    #pragma unroll
    for (int u = 0; u < 2; ++u) {
      int q = t + u * 256;
      int row = q >> 2, kf = (q & 3) * 4;          // 128 rows x 4 float4 of k
      float4 a = *(const float4*)(xb + (size_t)(i0 + row) * H + kc + kf);
      As[kf + 0][row] = a.x; As[kf + 1][row] = a.y;
      As[kf + 2][row] = a.z; As[kf + 3][row] = a.w;
      float4 bv = *(const float4*)(xb + (size_t)(j0 + row) * H + kc + kf);
      Bs[kf + 0][row] = bv.x; Bs[kf + 1][row] = bv.y;
      Bs[kf + 2][row] = bv.z; Bs[kf + 3][row] = bv.w;
    }
    __syncthreads();
    #pragma unroll
    for (int kk = 0; kk < 16; ++kk) {
      float4 a0 = *(const float4*)&As[kk][ty * 4];
      float4 a1 = *(const float4*)&As[kk][64 + ty * 4];
      float4 b0 = *(const float4*)&Bs[kk][tx * 4];
      float4 b1 = *(const float4*)&Bs[kk][64 + tx * 4];
      float ar[8] = {a0.x,a0.y,a0.z,a0.w,a1.x,a1.y,a1.z,a1.w};
      float br[8] = {b0.x,b0.y,b0.z,b0.w,b1.x,b1.y,b1.z,b1.w};
      #pragma unroll
      for (int r = 0; r < 8; ++r)
        #pragma unroll
        for (int c = 0; c < 8; ++c) acc[r][c] += ar[r] * br[c];
    }
    __syncthreads();
  }
  float n2i[8], n2j[8];
  #pragma unroll
  for (int r = 0; r < 8; ++r)
    n2i[r] = n2[bb * N + i0 + (r < 4 ? ty * 4 + r : 64 + ty * 4 + r - 4)];
  #pragma unroll
  for (int c = 0; c < 8; ++c)
    n2j[c] = n2[bb * N + j0 + (c < 4 ? tx * 4 + c : 64 + tx * 4 + c - 4)];
  #pragma unroll
  for (int r = 0; r < 8; ++r) {
    int mi = i0 + (r < 4 ? ty * 4 + r : 64 + ty * 4 + r - 4);
    float o[8];
    #pragma unroll
    for (int c = 0; c < 8; ++c) {
      float d2 = (n2i[r] + n2j[c]) - 2.0f * acc[r][c];
      o[c] = sqrtf(fmaxf(d2, 0.0f));
    }
    float* dst = dist + ((size_t)bb * N + mi) * N + j0;
    *(float4*)(dst + tx * 4)      = make_float4(o[0], o[1], o[2], o[3]);
    *(float4*)(dst + 64 + tx * 4) = make_float4(o[4], o[5], o[6], o[7]);
  }
}

// ---------------- Prim MST -------------------------------------------------------
// 1 wave/batch. Node j: lane j>>4, slot j&15. Weights compared as u32 bits (valid
// for non-negative floats). Selection = DPP row_shr min + 2 shfl_xor + readlane;
// index recovered via ballot (lowest lane) + ffs of match mask (lowest slot) ==
// jnp.argmin first-index semantics. Old-state argmin (A) is computed while the
// winner row is in flight; incoming-row argmin (R) combines after. Parent in LDS.
struct Sel { unsigned w; int gj; };

__device__ __forceinline__ unsigned wave_min_u32(unsigned x) {
  unsigned t;
  t = (unsigned)__builtin_amdgcn_update_dpp((int)x, (int)x, 0x111, 0xf, 0xf, false); x = umin32(x, t);
  t = (unsigned)__builtin_amdgcn_update_dpp((int)x, (int)x, 0x112, 0xf, 0xf, false); x = umin32(x, t);
  t = (unsigned)__builtin_amdgcn_update_dpp((int)x, (int)x, 0x114, 0xf, 0xf, false); x = umin32(x, t);
  t = (unsigned)__builtin_amdgcn_update_dpp((int)x, (int)x, 0x118, 0xf, 0xf, false); x = umin32(x, t);
  x = umin32(x, (unsigned)__shfl_xor((int)x, 16));
  x = umin32(x, (unsigned)__shfl_xor((int)x, 32));
  return (unsigned)__builtin_amdgcn_readlane((int)x, 63);
}

__device__ __forceinline__ Sel select_min(const unsigned* v) {
  unsigned t8[8], t4[4], t2[2];
  #pragma unroll
  for (int i = 0; i < 8; ++i) t8[i] = umin32(v[i], v[i + 8]);
  #pragma unroll
  for (int i = 0; i < 4; ++i) t4[i] = umin32(t8[i], t8[i + 4]);
  t2[0] = umin32(t4[0], t4[2]); t2[1] = umin32(t4[1], t4[3]);
  unsigned lm = umin32(t2[0], t2[1]);
  unsigned ws = wave_min_u32(lm);
  unsigned mbits = 0;
  #pragma unroll
  for (int s = 0; s < 16; ++s) mbits |= (v[s] == ws ? 1u : 0u) << s;
  unsigned long long bal = __ballot(mbits != 0);
  int fl = __ffsll(bal) - 1;
  int slot = __ffs(__builtin_amdgcn_readlane((int)mbits, fl)) - 1;
  Sel r; r.w = ws; r.gj = fl * 16 + slot;
  return r;
}

__global__ void prim_kernel(const float* __restrict__ dist,
    int* __restrict__ ep, int* __restrict__ ev, float* __restrict__ ewt) {
  __shared__ int par[N];
  const int b = blockIdx.x, lane = threadIdx.x;      // 64 threads
  const float* Db = dist + (size_t)b * N * N;
  const int jbase = lane * 16;
  int* epb = ep + b * NE;
  int* evb = ev + b * NE;
  float* ewb = ewt + b * NE;

  #pragma unroll
  for (int u = 0; u < 16; ++u) par[u * 64 + lane] = 0;

  unsigned mind[16], mw[16], rmask[16];
  {
    const float4* rp = (const float4*)Db;            // row 0
    #pragma unroll
    for (int u = 0; u < 4; ++u) {
      float4 v = rp[lane * 4 + u];
      mind[4*u+0] = __float_as_uint(v.x); mind[4*u+1] = __float_as_uint(v.y);
      mind[4*u+2] = __float_as_uint(v.z); mind[4*u+3] = __float_as_uint(v.w);
    }
  }
  #pragma unroll
  for (int s = 0; s < 16; ++s) { rmask[s] = 0u; mw[s] = mind[s]; }
  if (lane == 0) { rmask[0] = ~0u; mw[0] = ~0u; }    // node 0 in tree

  Sel s0 = select_min(mw);
  int cj = s0.gj;
  if (lane == 0) { epb[0] = 0; evb[0] = cj; ewb[0] = __uint_as_float(s0.w); }
  if (lane == (cj >> 4)) { rmask[cj & 15] = ~0u; mw[cj & 15] = ~0u; }

  float4 r0, r1, r2, r3;
  {
    const float4* rp = (const float4*)(Db + (size_t)cj * N);
    r0 = rp[lane * 4]; r1 = rp[lane * 4 + 1]; r2 = rp[lane * 4 + 2]; r3 = rp[lane * 4 + 3];
  }

  for (int k = 1; k < NE; ++k) {
    Sel sa = select_min(mw);                         // over OLD state; hides load latency
    unsigned rv[16];
    rv[0]=__float_as_uint(r0.x);  rv[1]=__float_as_uint(r0.y);
    rv[2]=__float_as_uint(r0.z);  rv[3]=__float_as_uint(r0.w);
    rv[4]=__float_as_uint(r1.x);  rv[5]=__float_as_uint(r1.y);
    rv[6]=__float_as_uint(r1.z);  rv[7]=__float_as_uint(r1.w);
    rv[8]=__float_as_uint(r2.x);  rv[9]=__float_as_uint(r2.y);
    rv[10]=__float_as_uint(r2.z); rv[11]=__float_as_uint(r2.w);
    rv[12]=__float_as_uint(r3.x); rv[13]=__float_as_uint(r3.y);
    rv[14]=__float_as_uint(r3.z); rv[15]=__float_as_uint(r3.w);
    unsigned rvm[16];
    #pragma unroll
    for (int s = 0; s < 16; ++s) rvm[s] = rv[s] | rmask[s];  // in-tree -> 0xFFFFFFFF
    #pragma unroll
    for (int s = 0; s < 16; ++s) {
      bool upd = rv[s] < mind[s];                    // strict <, matches reference
      if (upd) { par[jbase + s] = cj; mind[s] = rv[s]; }
      mw[s] = umin32(mw[s], rvm[s]);
    }
    Sel sr = select_min(rvm);                        // over the new row only
    unsigned w; int nj;
    if (sa.w < sr.w)      { w = sa.w; nj = sa.gj; }
    else if (sr.w < sa.w) { w = sr.w; nj = sr.gj; }
    else                  { w = sa.w; nj = sa.gj < sr.gj ? sa.gj : sr.gj; }
    if (lane == 0) { epb[k] = par[nj]; evb[k] = nj; ewb[k] = __uint_as_float(w); }
    if (lane == (nj >> 4)) { rmask[nj & 15] = ~0u; mw[nj & 15] = ~0u; }
    cj = nj;
    const float4* rp = (const float4*)(Db + (size_t)cj * N);
    r0 = rp[lane * 4]; r1 = rp[lane * 4 + 1]; r2 = rp[lane * 4 + 2]; r3 = rp[lane * 4 + 3];
  }
}

// ---------------- adjacency + deg^-1/2 (deterministic, no atomics) --------------
__global__ void adj_kernel(const int* __restrict__ ep, const int* __restrict__ ev,
    const float* __restrict__ ewt, int* __restrict__ adjI, float* __restrict__ adjW,
    int* __restrict__ cnt, float* __restrict__ dinv) {
  int i = blockIdx.x * 256 + threadIdx.x;
  int b = i >> 10, loc = i & 1023;
  const int* epb = ep + b * NE;
  const int* evb = ev + b * NE;
  const float* ewb = ewt + b * NE;
  int c = 0; float wsum = 0.0f;
  for (int k = 0; k < NE; ++k) {
    int p = epb[k], v = evb[k];
    if (p == loc || v == loc) {
      float w = ewb[k];
      wsum += w;
      int nb = (p == loc) ? v : p;
      if (c < CAP) { adjI[i * CAP + c] = (b << 10) + nb; adjW[i * CAP + c] = w; }
      ++c;
    }
  }
  cnt[i]  = c < CAP ? c : CAP;
  dinv[i] = 1.0f / sqrtf(wsum + 1.0f);
}

// ---------------- SSG propagation: h = alpha*x + (1-alpha)*A_hat x --------------
template <int HH>
__global__ void prop_kernel(const float* __restrict__ x, const int* __restrict__ adjI,
    const float* __restrict__ adjW, const int* __restrict__ cnt,
    const float* __restrict__ dinv, float* __restrict__ h) {
  constexpr int U = HH / 256;
  int wave = threadIdx.x >> 6, lane = threadIdx.x & 63;
  int i = blockIdx.x * 4 + wave;
  float dv = dinv[i];
  int c = cnt[i];
  float selfc = ALPHA + (1.0f - ALPHA) * dv * dv;
  float4 acc[U];
  const float* xi = x + (size_t)i * HH + lane * 4;
  #pragma unroll
  for (int u = 0; u < U; ++u) {
    float4 v = *(const float4*)(xi + u * 256);
    acc[u].x = selfc * v.x; acc[u].y = selfc * v.y;
    acc[u].z = selfc * v.z; acc[u].w = selfc * v.w;
  }
  for (int e = 0; e < c; ++e) {
    int j   = adjI[i * CAP + e];
    float w = adjW[i * CAP + e];
    float coef = (1.0f - ALPHA) * dv * (w * dinv[j]);
    const float* xj = x + (size_t)j * HH + lane * 4;
    #pragma unroll
    for (int u = 0; u < U; ++u) {
      float4 v = *(const float4*)(xj + u * 256);
      acc[u].x += coef * v.x; acc[u].y += coef * v.y;
      acc[u].z += coef * v.z; acc[u].w += coef * v.w;
    }
  }
  float* ho = h + (size_t)i * HH + lane * 4;
  #pragma unroll
  for (int u = 0; u < U; ++u) *(float4*)(ho + u * 256) = acc[u];
}

// ---------------- fused GEMM + bias + tanh: 128x128 tile, 8x8 per thread --------
template <int K>
__global__ __launch_bounds__(256) void gemm_tanh_kernel(const float* __restrict__ A,
    const float* __restrict__ W, const float* __restrict__ bias, float* __restrict__ C) {
  __shared__ float As[16][132], Bs[16][132];
  const int m0 = blockIdx.x * 128, n0 = blockIdx.y * 128;
  const int t = threadIdx.x, tx = t & 15, ty = t >> 4;
  float acc[8][8] = {};
  for (int kc = 0; kc < K; kc += 16) {
    #pragma unroll
    for (int u = 0; u < 2; ++u) {
      int q = t + u * 256;
      int row = q >> 2, kf = (q & 3) * 4;
      float4 a = *(const float4*)(A + (size_t)(m0 + row) * K + kc + kf);
      As[kf + 0][row] = a.x; As[kf + 1][row] = a.y;
      As[kf + 2][row] = a.z; As[kf + 3][row] = a.w;
      int rowB = q >> 5, cf = (q & 31) * 4;
      *(float4*)&Bs[rowB][cf] = *(const float4*)(W + (size_t)(kc + rowB) * H2 + n0 + cf);
    }
    __syncthreads();
    #pragma unroll
    for (int kk = 0; kk < 16; ++kk) {
      float4 a0 = *(const float4*)&As[kk][ty * 4];
      float4 a1 = *(const float4*)&As[kk][64 + ty * 4];
      float4 b0 = *(const float4*)&Bs[kk][tx * 4];
      float4 b1 = *(const float4*)&Bs[kk][64 + tx * 4];
      float ar[8] = {a0.x,a0.y,a0.z,a0.w,a1.x,a1.y,a1.z,a1.w};
      float br[8] = {b0.x,b0.y,b0.z,b0.w,b1.x,b1.y,b1.z,b1.w};
      #pragma unroll
      for (int r = 0; r < 8; ++r)
        #pragma unroll
        for (int c = 0; c < 8; ++c) acc[r][c] += ar[r] * br[c];
    }
    __syncthreads();
  }
  float4 bi0 = *(const float4*)(bias + n0 + tx * 4);
  float4 bi1 = *(const float4*)(bias + n0 + 64 + tx * 4);
  float bb[8] = {bi0.x,bi0.y,bi0.z,bi0.w,bi1.x,bi1.y,bi1.z,bi1.w};
  #pragma unroll
  for (int r = 0; r < 8; ++r) {
    int m = m0 + (r < 4 ? ty * 4 + r : 64 + ty * 4 + r - 4);
    float o[8];
    #pragma unroll
    for (int c = 0; c < 8; ++c) o[c] = tanhf(acc[r][c] + bb[c]);
    float* dst = C + (size_t)m * H2 + n0;
    *(float4*)(dst + tx * 4)      = make_float4(o[0], o[1], o[2], o[3]);
    *(float4*)(dst + 64 + tx * 4) = make_float4(o[4], o[5], o[6], o[7]);
  }
}

// ---------------- mean pool over N nodes per graph ------------------------------
__global__ void pool_kernel(const float* __restrict__ x, float* __restrict__ pooled) {
  int b = blockIdx.x;
  int c = blockIdx.y * 256 + threadIdx.x;
  const float* xb = x + ((size_t)b << 10) * H2 + c;
  float s = 0.0f;
  for (int i = 0; i < N; ++i) s += xb[(size_t)i * H2];
  pooled[b * H2 + c] = s * (1.0f / N);
}

// ---------------- dense head: tanh(pooled@Wd+bd) @ Wo + bo ----------------------
__global__ void head_kernel(const float* __restrict__ pooled, const float* __restrict__ Wd,
    const float* __restrict__ bd, const float* __restrict__ Wo, const float* __restrict__ bo,
    float* __restrict__ out) {
  __shared__ float sp[512], sh[256];
  int b = blockIdx.x, t = threadIdx.x;
  sp[t] = pooled[b * H2 + t];
  sp[t + 256] = pooled[b * H2 + t + 256];
  __syncthreads();
  float acc = bd[t];
  for (int c2 = 0; c2 < 512; ++c2) acc += sp[c2] * Wd[c2 * 256 + t];
  sh[t] = tanhf(acc);
  __syncthreads();
  if (t < 8) {
    float o = bo[t];
    for (int j = 0; j < 256; ++j) o += sh[j] * Wo[j * 8 + t];
    out[b * 8 + t] = o;
  }
}

}  // namespace

extern "C" void kernel_launch(void* const* d_in, const int* in_sizes, int n_in,
                              void* d_out, int out_size, void* d_ws, size_t ws_size,
                              hipStream_t stream) {
  const float* feat = (const float*)d_in[0];
  const float* W1 = (const float*)d_in[1];
  const float* b1 = (const float*)d_in[2];
  const float* W2 = (const float*)d_in[3];
  const float* b2 = (const float*)d_in[4];
  const float* W3 = (const float*)d_in[5];
  const float* b3 = (const float*)d_in[6];
  const float* Wd = (const float*)d_in[7];
  const float* bd = (const float*)d_in[8];
  const float* Wo = (const float*)d_in[9];
  const float* bo = (const float*)d_in[10];
  float* out = (float*)d_out;
  char* ws = (char*)d_ws;

  float* dist = (float*)(ws);
  float* xcur = (float*)(ws);                        // reuses dist after prim
  float* hbuf = (float*)(ws + ((size_t)64 << 20));
  char* misc  = ws + ((size_t)96 << 20);
  int*   ep     = (int*)(misc);
  int*   ev     = (int*)(misc + 65536);
  float* ewt    = (float*)(misc + 131072);
  int*   cnt    = (int*)(misc + 196608);
  float* dinv   = (float*)(misc + 262144);
  int*   adjI   = (int*)(misc + 327680);
  float* adjW   = (float*)(misc + 327680 + 2097152);
  float* n2     = (float*)(misc + 327680 + 2 * 2097152);
  float* pooled = (float*)(misc + 327680 + 2 * 2097152 + 65536);

  n2_kernel<<<NT / 4, 256, 0, stream>>>(feat, n2);
  dist_kernel<<<dim3(8, 8, 16), 256, 0, stream>>>(feat, n2, dist);
  prim_kernel<<<B, 64, 0, stream>>>(dist, ep, ev, ewt);
  adj_kernel<<<NT / 256, 256, 0, stream>>>(ep, ev, ewt, adjI, adjW, cnt, dinv);

  prop_kernel<256><<<NT / 4, 256, 0, stream>>>(feat, adjI, adjW, cnt, dinv, hbuf);
  gemm_tanh_kernel<256><<<dim3(NT / 128, 4), 256, 0, stream>>>(hbuf, W1, b1, xcur);
  prop_kernel<512><<<NT / 4, 256, 0, stream>>>(xcur, adjI, adjW, cnt, dinv, hbuf);
  gemm_tanh_kernel<512><<<dim3(NT / 128, 4), 256, 0, stream>>>(hbuf, W2, b2, xcur);
  prop_kernel<512><<<NT / 4, 256, 0, stream>>>(xcur, adjI, adjW, cnt, dinv, hbuf);
  gemm_tanh_kernel<512><<<dim3(NT / 128, 4), 256, 0, stream>>>(hbuf, W3, b3, xcur);

  pool_kernel<<<dim3(B, H2 / 256), 256, 0, stream>>>(xcur, pooled);
  head_kernel<<<B, 256, 0, stream>>>(pooled, Wd, bd, Wo, bo, out);
}

// Round 4
// 1676.164 us; speedup vs baseline: 1.2347x; 1.0320x over previous
//
#include <hip/hip_runtime.h>
#include <math.h>

namespace {

constexpr float ALPHA = 0.3f;
constexpr int B  = 16;
constexpr int N  = 1024;
constexpr int H  = 256;
constexpr int H2 = 512;
constexpr int NT = B * N;        // 16384 total nodes
constexpr int NE = N - 1;        // 1023 MST edges per batch
constexpr int CAP = 32;          // adjacency capacity per node (MST degree << 32)

__device__ __forceinline__ unsigned umin32(unsigned a, unsigned b) { return a < b ? a : b; }

// ---------------- row squared-norms: n2[row] = sum_k x[row][k]^2 ----------------
__global__ void n2_kernel(const float* __restrict__ x, float* __restrict__ n2) {
  int wave = threadIdx.x >> 6, lane = threadIdx.x & 63;
  int row  = blockIdx.x * 4 + wave;
  float4 v = *(const float4*)(x + (size_t)row * H + lane * 4);
  float s  = v.x * v.x + v.y * v.y + v.z * v.z + v.w * v.w;
  #pragma unroll
  for (int off = 32; off; off >>= 1) s += __shfl_xor(s, off);
  if (lane == 0) n2[row] = s;
}

// ---------------- distance matrix: 128x128 tile, 8x8 per thread -----------------
__global__ __launch_bounds__(256) void dist_kernel(const float* __restrict__ x,
    const float* __restrict__ n2, float* __restrict__ dist) {
  __shared__ float As[16][132], Bs[16][132];
  const int bb = blockIdx.z;
  const int i0 = blockIdx.y * 128, j0 = blockIdx.x * 128;
  const int t = threadIdx.x, tx = t & 15, ty = t >> 4;
  const float* xb = x + (size_t)bb * N * H;
  float acc[8][8] = {};
  for (int kc = 0; kc < H; kc += 16) {
    #pragma unroll
    for (int u = 0; u < 2; ++u) {
      int q = t + u * 256;
      int row = q >> 2, kf = (q & 3) * 4;          // 128 rows x 4 float4 of k
      float4 a = *(const float4*)(xb + (size_t)(i0 + row) * H + kc + kf);
      As[kf + 0][row] = a.x; As[kf + 1][row] = a.y;
      As[kf + 2][row] = a.z; As[kf + 3][row] = a.w;
      float4 bv = *(const float4*)(xb + (size_t)(j0 + row) * H + kc + kf);
      Bs[kf + 0][row] = bv.x; Bs[kf + 1][row] = bv.y;
      Bs[kf + 2][row] = bv.z; Bs[kf + 3][row] = bv.w;
    }
    __syncthreads();
    #pragma unroll
    for (int kk = 0; kk < 16; ++kk) {
      float4 a0 = *(const float4*)&As[kk][ty * 4];
      float4 a1 = *(const float4*)&As[kk][64 + ty * 4];
      float4 b0 = *(const float4*)&Bs[kk][tx * 4];
      float4 b1 = *(const float4*)&Bs[kk][64 + tx * 4];
      float ar[8] = {a0.x,a0.y,a0.z,a0.w,a1.x,a1.y,a1.z,a1.w};
      float br[8] = {b0.x,b0.y,b0.z,b0.w,b1.x,b1.y,b1.z,b1.w};
      #pragma unroll
      for (int r = 0; r < 8; ++r)
        #pragma unroll
        for (int c = 0; c < 8; ++c) acc[r][c] += ar[r] * br[c];
    }
    __syncthreads();
  }
  float n2i[8], n2j[8];
  #pragma unroll
  for (int r = 0; r < 8; ++r)
    n2i[r] = n2[bb * N + i0 + (r < 4 ? ty * 4 + r : 64 + ty * 4 + r - 4)];
  #pragma unroll
  for (int c = 0; c < 8; ++c)
    n2j[c] = n2[bb * N + j0 + (c < 4 ? tx * 4 + c : 64 + tx * 4 + c - 4)];
  #pragma unroll
  for (int r = 0; r < 8; ++r) {
    int mi = i0 + (r < 4 ? ty * 4 + r : 64 + ty * 4 + r - 4);
    float o[8];
    #pragma unroll
    for (int c = 0; c < 8; ++c) {
      float d2 = (n2i[r] + n2j[c]) - 2.0f * acc[r][c];
      o[c] = sqrtf(fmaxf(d2, 0.0f));
    }
    float* dst = dist + ((size_t)bb * N + mi) * N + j0;
    *(float4*)(dst + tx * 4)      = make_float4(o[0], o[1], o[2], o[3]);
    *(float4*)(dst + 64 + tx * 4) = make_float4(o[4], o[5], o[6], o[7]);
  }
}

// ---------------- Prim MST with speculative next-row prefetch --------------------
// 1 wave/batch. Node j: lane j>>4, slot j&15. Weights compared as u32 bits.
// Selection k = combine(sa over pre-row state [computed while row in flight],
// sr over the incoming row). sa.gj is also the PREDICTED next winner: its row is
// speculatively loaded into the spare buffer; on miss (sr won) it is re-issued.
// Tie-breaking identical to jnp.argmin (lowest index at min weight).
struct Sel { unsigned w; int gj; };

__device__ __forceinline__ unsigned wave_min_u32(unsigned x) {
  unsigned t;
  t = (unsigned)__builtin_amdgcn_update_dpp((int)x, (int)x, 0x111, 0xf, 0xf, false); x = umin32(x, t);
  t = (unsigned)__builtin_amdgcn_update_dpp((int)x, (int)x, 0x112, 0xf, 0xf, false); x = umin32(x, t);
  t = (unsigned)__builtin_amdgcn_update_dpp((int)x, (int)x, 0x114, 0xf, 0xf, false); x = umin32(x, t);
  t = (unsigned)__builtin_amdgcn_update_dpp((int)x, (int)x, 0x118, 0xf, 0xf, false); x = umin32(x, t);
  x = umin32(x, (unsigned)__shfl_xor((int)x, 16));
  x = umin32(x, (unsigned)__shfl_xor((int)x, 32));
  return (unsigned)__builtin_amdgcn_readlane((int)x, 63);
}

__device__ __forceinline__ Sel select_min(const unsigned* v) {
  unsigned t8[8], t4[4], t2[2];
  #pragma unroll
  for (int i = 0; i < 8; ++i) t8[i] = umin32(v[i], v[i + 8]);
  #pragma unroll
  for (int i = 0; i < 4; ++i) t4[i] = umin32(t8[i], t8[i + 4]);
  t2[0] = umin32(t4[0], t4[2]); t2[1] = umin32(t4[1], t4[3]);
  unsigned lm = umin32(t2[0], t2[1]);
  unsigned ws = wave_min_u32(lm);
  unsigned mbits = 0;
  #pragma unroll
  for (int s = 0; s < 16; ++s) mbits |= (v[s] == ws ? 1u : 0u) << s;
  unsigned long long bal = __ballot(mbits != 0);
  int fl = __ffsll(bal) - 1;
  int slot = __ffs(__builtin_amdgcn_readlane((int)mbits, fl)) - 1;
  Sel r; r.w = ws; r.gj = fl * 16 + slot;
  return r;
}

// One Prim step consuming row regs C0..C3 (node cj), prefetching into X0..X3.
#define PRIM_ITER(kk, C0, C1, C2, C3, X0, X1, X2, X3)                            \
  {                                                                              \
    Sel sa = select_min(mw);                       /* prediction, pre-row */     \
    {                                              /* speculative prefetch */    \
      const float4* rp = (const float4*)(Db + (size_t)sa.gj * N);                \
      X0 = rp[lane * 4];     X1 = rp[lane * 4 + 1];                              \
      X2 = rp[lane * 4 + 2]; X3 = rp[lane * 4 + 3];                              \
    }                                                                            \
    unsigned rv[16];                               /* waits on CUR row only */   \
    rv[0]=__float_as_uint(C0.x);  rv[1]=__float_as_uint(C0.y);                   \
    rv[2]=__float_as_uint(C0.z);  rv[3]=__float_as_uint(C0.w);                   \
    rv[4]=__float_as_uint(C1.x);  rv[5]=__float_as_uint(C1.y);                   \
    rv[6]=__float_as_uint(C1.z);  rv[7]=__float_as_uint(C1.w);                   \
    rv[8]=__float_as_uint(C2.x);  rv[9]=__float_as_uint(C2.y);                   \
    rv[10]=__float_as_uint(C2.z); rv[11]=__float_as_uint(C2.w);                  \
    rv[12]=__float_as_uint(C3.x); rv[13]=__float_as_uint(C3.y);                  \
    rv[14]=__float_as_uint(C3.z); rv[15]=__float_as_uint(C3.w);                  \
    unsigned rvm[16];                                                            \
    _Pragma("unroll")                                                            \
    for (int s = 0; s < 16; ++s) rvm[s] = rv[s] | rmask[s];                      \
    Sel sr = select_min(rvm);                                                    \
    unsigned w; int nj;                                                          \
    if (sa.w < sr.w)      { w = sa.w; nj = sa.gj; }                              \
    else if (sr.w < sa.w) { w = sr.w; nj = sr.gj; }                              \
    else                  { w = sa.w; nj = sa.gj < sr.gj ? sa.gj : sr.gj; }      \
    if (nj != sa.gj) {                             /* miss: re-issue (uniform)*/ \
      const float4* rp = (const float4*)(Db + (size_t)nj * N);                   \
      X0 = rp[lane * 4];     X1 = rp[lane * 4 + 1];                              \
      X2 = rp[lane * 4 + 2]; X3 = rp[lane * 4 + 3];                              \
    }                                                                            \
    _Pragma("unroll")                                                            \
    for (int s = 0; s < 16; ++s) {                                               \
      bool upd = rv[s] < mind[s];                  /* strict <, matches ref */   \
      if (upd) { par[jbase + s] = cj; mind[s] = rv[s]; }                         \
      mw[s] = umin32(mw[s], rvm[s]);                                             \
    }                                                                            \
    if (lane == (nj >> 4)) { rmask[nj & 15] = ~0u; mw[nj & 15] = ~0u; }          \
    if (lane == 0) { epb[kk] = par[nj]; evb[kk] = nj; ewb[kk] = __uint_as_float(w); } \
    cj = nj;                                                                     \
  }

__global__ __launch_bounds__(64, 1) void prim_kernel(const float* __restrict__ dist,
    int* __restrict__ ep, int* __restrict__ ev, float* __restrict__ ewt) {
  __shared__ int par[N];
  const int b = blockIdx.x, lane = threadIdx.x;      // 64 threads
  const float* Db = dist + (size_t)b * N * N;
  const int jbase = lane * 16;
  int* epb = ep + b * NE;
  int* evb = ev + b * NE;
  float* ewb = ewt + b * NE;

  #pragma unroll
  for (int u = 0; u < 16; ++u) par[u * 64 + lane] = 0;

  unsigned mind[16], mw[16], rmask[16];
  {
    const float4* rp = (const float4*)Db;            // row 0
    #pragma unroll
    for (int u = 0; u < 4; ++u) {
      float4 v = rp[lane * 4 + u];
      mind[4*u+0] = __float_as_uint(v.x); mind[4*u+1] = __float_as_uint(v.y);
      mind[4*u+2] = __float_as_uint(v.z); mind[4*u+3] = __float_as_uint(v.w);
    }
  }
  #pragma unroll
  for (int s = 0; s < 16; ++s) { rmask[s] = 0u; mw[s] = mind[s]; }
  if (lane == 0) { rmask[0] = ~0u; mw[0] = ~0u; }    // node 0 in tree

  Sel s0 = select_min(mw);
  int cj = s0.gj;
  if (lane == 0) { epb[0] = 0; evb[0] = cj; ewb[0] = __uint_as_float(s0.w); }
  if (lane == (cj >> 4)) { rmask[cj & 15] = ~0u; mw[cj & 15] = ~0u; }

  float4 a0, a1, a2, a3, b0, b1, b2, b3;
  {
    const float4* rp = (const float4*)(Db + (size_t)cj * N);
    a0 = rp[lane * 4]; a1 = rp[lane * 4 + 1]; a2 = rp[lane * 4 + 2]; a3 = rp[lane * 4 + 3];
  }

  for (int k = 1; k + 1 < NE; k += 2) {              // NE-1 = 1022 iters, even
    PRIM_ITER(k,     a0, a1, a2, a3, b0, b1, b2, b3);
    PRIM_ITER(k + 1, b0, b1, b2, b3, a0, a1, a2, a3);
  }
}

// ---------------- adjacency + deg^-1/2 (deterministic, no atomics) --------------
__global__ void adj_kernel(const int* __restrict__ ep, const int* __restrict__ ev,
    const float* __restrict__ ewt, int* __restrict__ adjI, float* __restrict__ adjW,
    int* __restrict__ cnt, float* __restrict__ dinv) {
  int i = blockIdx.x * 256 + threadIdx.x;
  int b = i >> 10, loc = i & 1023;
  const int* epb = ep + b * NE;
  const int* evb = ev + b * NE;
  const float* ewb = ewt + b * NE;
  int c = 0; float wsum = 0.0f;
  for (int k = 0; k < NE; ++k) {
    int p = epb[k], v = evb[k];
    if (p == loc || v == loc) {
      float w = ewb[k];
      wsum += w;
      int nb = (p == loc) ? v : p;
      if (c < CAP) { adjI[i * CAP + c] = (b << 10) + nb; adjW[i * CAP + c] = w; }
      ++c;
    }
  }
  cnt[i]  = c < CAP ? c : CAP;
  dinv[i] = 1.0f / sqrtf(wsum + 1.0f);
}

// ---------------- SSG propagation: h = alpha*x + (1-alpha)*A_hat x --------------
template <int HH>
__global__ void prop_kernel(const float* __restrict__ x, const int* __restrict__ adjI,
    const float* __restrict__ adjW, const int* __restrict__ cnt,
    const float* __restrict__ dinv, float* __restrict__ h) {
  constexpr int U = HH / 256;
  int wave = threadIdx.x >> 6, lane = threadIdx.x & 63;
  int i = blockIdx.x * 4 + wave;
  float dv = dinv[i];
  int c = cnt[i];
  float selfc = ALPHA + (1.0f - ALPHA) * dv * dv;
  float4 acc[U];
  const float* xi = x + (size_t)i * HH + lane * 4;
  #pragma unroll
  for (int u = 0; u < U; ++u) {
    float4 v = *(const float4*)(xi + u * 256);
    acc[u].x = selfc * v.x; acc[u].y = selfc * v.y;
    acc[u].z = selfc * v.z; acc[u].w = selfc * v.w;
  }
  for (int e = 0; e < c; ++e) {
    int j   = adjI[i * CAP + e];
    float w = adjW[i * CAP + e];
    float coef = (1.0f - ALPHA) * dv * (w * dinv[j]);
    const float* xj = x + (size_t)j * HH + lane * 4;
    #pragma unroll
    for (int u = 0; u < U; ++u) {
      float4 v = *(const float4*)(xj + u * 256);
      acc[u].x += coef * v.x; acc[u].y += coef * v.y;
      acc[u].z += coef * v.z; acc[u].w += coef * v.w;
    }
  }
  float* ho = h + (size_t)i * HH + lane * 4;
  #pragma unroll
  for (int u = 0; u < U; ++u) *(float4*)(ho + u * 256) = acc[u];
}

// ---------------- fused GEMM + bias + tanh: 128x128 tile, 8x8 per thread --------
template <int K>
__global__ __launch_bounds__(256) void gemm_tanh_kernel(const float* __restrict__ A,
    const float* __restrict__ W, const float* __restrict__ bias, float* __restrict__ C) {
  __shared__ float As[16][132], Bs[16][132];
  const int m0 = blockIdx.x * 128, n0 = blockIdx.y * 128;
  const int t = threadIdx.x, tx = t & 15, ty = t >> 4;
  float acc[8][8] = {};
  for (int kc = 0; kc < K; kc += 16) {
    #pragma unroll
    for (int u = 0; u < 2; ++u) {
      int q = t + u * 256;
      int row = q >> 2, kf = (q & 3) * 4;
      float4 a = *(const float4*)(A + (size_t)(m0 + row) * K + kc + kf);
      As[kf + 0][row] = a.x; As[kf + 1][row] = a.y;
      As[kf + 2][row] = a.z; As[kf + 3][row] = a.w;
      int rowB = q >> 5, cf = (q & 31) * 4;
      *(float4*)&Bs[rowB][cf] = *(const float4*)(W + (size_t)(kc + rowB) * H2 + n0 + cf);
    }
    __syncthreads();
    #pragma unroll
    for (int kk = 0; kk < 16; ++kk) {
      float4 a0 = *(const float4*)&As[kk][ty * 4];
      float4 a1 = *(const float4*)&As[kk][64 + ty * 4];
      float4 b0 = *(const float4*)&Bs[kk][tx * 4];
      float4 b1 = *(const float4*)&Bs[kk][64 + tx * 4];
      float ar[8] = {a0.x,a0.y,a0.z,a0.w,a1.x,a1.y,a1.z,a1.w};
      float br[8] = {b0.x,b0.y,b0.z,b0.w,b1.x,b1.y,b1.z,b1.w};
      #pragma unroll
      for (int r = 0; r < 8; ++r)
        #pragma unroll
        for (int c = 0; c < 8; ++c) acc[r][c] += ar[r] * br[c];
    }
    __syncthreads();
  }
  float4 bi0 = *(const float4*)(bias + n0 + tx * 4);
  float4 bi1 = *(const float4*)(bias + n0 + 64 + tx * 4);
  float bb[8] = {bi0.x,bi0.y,bi0.z,bi0.w,bi1.x,bi1.y,bi1.z,bi1.w};
  #pragma unroll
  for (int r = 0; r < 8; ++r) {
    int m = m0 + (r < 4 ? ty * 4 + r : 64 + ty * 4 + r - 4);
    float o[8];
    #pragma unroll
    for (int c = 0; c < 8; ++c) o[c] = tanhf(acc[r][c] + bb[c]);
    float* dst = C + (size_t)m * H2 + n0;
    *(float4*)(dst + tx * 4)      = make_float4(o[0], o[1], o[2], o[3]);
    *(float4*)(dst + 64 + tx * 4) = make_float4(o[4], o[5], o[6], o[7]);
  }
}

// ---------------- mean pool over N nodes per graph ------------------------------
__global__ void pool_kernel(const float* __restrict__ x, float* __restrict__ pooled) {
  int b = blockIdx.x;
  int c = blockIdx.y * 256 + threadIdx.x;
  const float* xb = x + ((size_t)b << 10) * H2 + c;
  float s = 0.0f;
  for (int i = 0; i < N; ++i) s += xb[(size_t)i * H2];
  pooled[b * H2 + c] = s * (1.0f / N);
}

// ---------------- dense head: tanh(pooled@Wd+bd) @ Wo + bo ----------------------
__global__ void head_kernel(const float* __restrict__ pooled, const float* __restrict__ Wd,
    const float* __restrict__ bd, const float* __restrict__ Wo, const float* __restrict__ bo,
    float* __restrict__ out) {
  __shared__ float sp[512], sh[256];
  int b = blockIdx.x, t = threadIdx.x;
  sp[t] = pooled[b * H2 + t];
  sp[t + 256] = pooled[b * H2 + t + 256];
  __syncthreads();
  float acc = bd[t];
  for (int c2 = 0; c2 < 512; ++c2) acc += sp[c2] * Wd[c2 * 256 + t];
  sh[t] = tanhf(acc);
  __syncthreads();
  if (t < 8) {
    float o = bo[t];
    for (int j = 0; j < 256; ++j) o += sh[j] * Wo[j * 8 + t];
    out[b * 8 + t] = o;
  }
}

}  // namespace

extern "C" void kernel_launch(void* const* d_in, const int* in_sizes, int n_in,
                              void* d_out, int out_size, void* d_ws, size_t ws_size,
                              hipStream_t stream) {
  const float* feat = (const float*)d_in[0];
  const float* W1 = (const float*)d_in[1];
  const float* b1 = (const float*)d_in[2];
  const float* W2 = (const float*)d_in[3];
  const float* b2 = (const float*)d_in[4];
  const float* W3 = (const float*)d_in[5];
  const float* b3 = (const float*)d_in[6];
  const float* Wd = (const float*)d_in[7];
  const float* bd = (const float*)d_in[8];
  const float* Wo = (const float*)d_in[9];
  const float* bo = (const float*)d_in[10];
  float* out = (float*)d_out;
  char* ws = (char*)d_ws;

  float* dist = (float*)(ws);
  float* xcur = (float*)(ws);                        // reuses dist after prim
  float* hbuf = (float*)(ws + ((size_t)64 << 20));
  char* misc  = ws + ((size_t)96 << 20);
  int*   ep     = (int*)(misc);
  int*   ev     = (int*)(misc + 65536);
  float* ewt    = (float*)(misc + 131072);
  int*   cnt    = (int*)(misc + 196608);
  float* dinv   = (float*)(misc + 262144);
  int*   adjI   = (int*)(misc + 327680);
  float* adjW   = (float*)(misc + 327680 + 2097152);
  float* n2     = (float*)(misc + 327680 + 2 * 2097152);
  float* pooled = (float*)(misc + 327680 + 2 * 2097152 + 65536);

  n2_kernel<<<NT / 4, 256, 0, stream>>>(feat, n2);
  dist_kernel<<<dim3(8, 8, 16), 256, 0, stream>>>(feat, n2, dist);
  prim_kernel<<<B, 64, 0, stream>>>(dist, ep, ev, ewt);
  adj_kernel<<<NT / 256, 256, 0, stream>>>(ep, ev, ewt, adjI, adjW, cnt, dinv);

  prop_kernel<256><<<NT / 4, 256, 0, stream>>>(feat, adjI, adjW, cnt, dinv, hbuf);
  gemm_tanh_kernel<256><<<dim3(NT / 128, 4), 256, 0, stream>>>(hbuf, W1, b1, xcur);
  prop_kernel<512><<<NT / 4, 256, 0, stream>>>(xcur, adjI, adjW, cnt, dinv, hbuf);
  gemm_tanh_kernel<512><<<dim3(NT / 128, 4), 256, 0, stream>>>(hbuf, W2, b2, xcur);
  prop_kernel<512><<<NT / 4, 256, 0, stream>>>(xcur, adjI, adjW, cnt, dinv, hbuf);
  gemm_tanh_kernel<512><<<dim3(NT / 128, 4), 256, 0, stream>>>(hbuf, W3, b3, xcur);

  pool_kernel<<<dim3(B, H2 / 256), 256, 0, stream>>>(xcur, pooled);
  head_kernel<<<B, 256, 0, stream>>>(pooled, Wd, bd, Wo, bo, out);
}

// Round 5
// 1649.924 us; speedup vs baseline: 1.2543x; 1.0159x over previous
//
#include <hip/hip_runtime.h>
#include <math.h>

namespace {

constexpr float ALPHA = 0.3f;
constexpr int B  = 16;
constexpr int N  = 1024;
constexpr int H  = 256;
constexpr int H2 = 512;
constexpr int NT = B * N;        // 16384 total nodes
constexpr int NE = N - 1;        // 1023 MST edges per batch
constexpr int CAP = 32;          // adjacency capacity per node (MST degree << 32)

__device__ __forceinline__ unsigned umin32(unsigned a, unsigned b) { return a < b ? a : b; }

// ---------------- row squared-norms: n2[row] = sum_k x[row][k]^2 ----------------
__global__ void n2_kernel(const float* __restrict__ x, float* __restrict__ n2) {
  int wave = threadIdx.x >> 6, lane = threadIdx.x & 63;
  int row  = blockIdx.x * 4 + wave;
  float4 v = *(const float4*)(x + (size_t)row * H + lane * 4);
  float s  = v.x * v.x + v.y * v.y + v.z * v.z + v.w * v.w;
  #pragma unroll
  for (int off = 32; off; off >>= 1) s += __shfl_xor(s, off);
  if (lane == 0) n2[row] = s;
}

// ---------------- distance matrix: 128x128 tile, 8x8 per thread -----------------
__global__ __launch_bounds__(256) void dist_kernel(const float* __restrict__ x,
    const float* __restrict__ n2, float* __restrict__ dist) {
  __shared__ float As[16][132], Bs[16][132];
  const int bb = blockIdx.z;
  const int i0 = blockIdx.y * 128, j0 = blockIdx.x * 128;
  const int t = threadIdx.x, tx = t & 15, ty = t >> 4;
  const float* xb = x + (size_t)bb * N * H;
  float acc[8][8] = {};
  for (int kc = 0; kc < H; kc += 16) {
    #pragma unroll
    for (int u = 0; u < 2; ++u) {
      int q = t + u * 256;
      int row = q >> 2, kf = (q & 3) * 4;          // 128 rows x 4 float4 of k
      float4 a = *(const float4*)(xb + (size_t)(i0 + row) * H + kc + kf);
      As[kf + 0][row] = a.x; As[kf + 1][row] = a.y;
      As[kf + 2][row] = a.z; As[kf + 3][row] = a.w;
      float4 bv = *(const float4*)(xb + (size_t)(j0 + row) * H + kc + kf);
      Bs[kf + 0][row] = bv.x; Bs[kf + 1][row] = bv.y;
      Bs[kf + 2][row] = bv.z; Bs[kf + 3][row] = bv.w;
    }
    __syncthreads();
    #pragma unroll
    for (int kk = 0; kk < 16; ++kk) {
      float4 a0 = *(const float4*)&As[kk][ty * 4];
      float4 a1 = *(const float4*)&As[kk][64 + ty * 4];
      float4 b0 = *(const float4*)&Bs[kk][tx * 4];
      float4 b1 = *(const float4*)&Bs[kk][64 + tx * 4];
      float ar[8] = {a0.x,a0.y,a0.z,a0.w,a1.x,a1.y,a1.z,a1.w};
      float br[8] = {b0.x,b0.y,b0.z,b0.w,b1.x,b1.y,b1.z,b1.w};
      #pragma unroll
      for (int r = 0; r < 8; ++r)
        #pragma unroll
        for (int c = 0; c < 8; ++c) acc[r][c] += ar[r] * br[c];
    }
    __syncthreads();
  }
  float n2i[8], n2j[8];
  #pragma unroll
  for (int r = 0; r < 8; ++r)
    n2i[r] = n2[bb * N + i0 + (r < 4 ? ty * 4 + r : 64 + ty * 4 + r - 4)];
  #pragma unroll
  for (int c = 0; c < 8; ++c)
    n2j[c] = n2[bb * N + j0 + (c < 4 ? tx * 4 + c : 64 + tx * 4 + c - 4)];
  #pragma unroll
  for (int r = 0; r < 8; ++r) {
    int mi = i0 + (r < 4 ? ty * 4 + r : 64 + ty * 4 + r - 4);
    float o[8];
    #pragma unroll
    for (int c = 0; c < 8; ++c) {
      float d2 = (n2i[r] + n2j[c]) - 2.0f * acc[r][c];
      o[c] = sqrtf(fmaxf(d2, 0.0f));
    }
    float* dst = dist + ((size_t)bb * N + mi) * N + j0;
    *(float4*)(dst + tx * 4)      = make_float4(o[0], o[1], o[2], o[3]);
    *(float4*)(dst + 64 + tx * 4) = make_float4(o[4], o[5], o[6], o[7]);
  }
}

// ---------------- Prim MST: speculative prefetch, WAW-free buffering -------------
// 1 wave/batch. Node j: lane j>>4, slot j&15. Weights as u32 bits (non-neg fp32).
// Per iter: sa = full argmin over frontier (computed while current row in flight;
// also the prediction for the next row -> spec load into S'); incoming row gets a
// WEIGHT-ONLY wave-min; index recovery for the row happens only on the rare
// miss/tie path (uniform branch) into a SEPARATE M buffer (never overwrites an
// in-flight load). Consume = useM ? M : S. Tie-break == jnp.argmin (lowest id).
__device__ __forceinline__ unsigned wave_min_u32(unsigned x) {
  unsigned t;
  t = (unsigned)__builtin_amdgcn_update_dpp((int)x, (int)x, 0x111, 0xf, 0xf, false); x = umin32(x, t);
  t = (unsigned)__builtin_amdgcn_update_dpp((int)x, (int)x, 0x112, 0xf, 0xf, false); x = umin32(x, t);
  t = (unsigned)__builtin_amdgcn_update_dpp((int)x, (int)x, 0x114, 0xf, 0xf, false); x = umin32(x, t);
  t = (unsigned)__builtin_amdgcn_update_dpp((int)x, (int)x, 0x118, 0xf, 0xf, false); x = umin32(x, t);
  x = umin32(x, (unsigned)__shfl_xor((int)x, 16));
  x = umin32(x, (unsigned)__shfl_xor((int)x, 32));
  return (unsigned)__builtin_amdgcn_readlane((int)x, 63);
}

__device__ __forceinline__ unsigned local_min16(const unsigned* v) {
  unsigned t8[8], t4[4], t2[2];
  #pragma unroll
  for (int i = 0; i < 8; ++i) t8[i] = umin32(v[i], v[i + 8]);
  #pragma unroll
  for (int i = 0; i < 4; ++i) t4[i] = umin32(t8[i], t8[i + 4]);
  t2[0] = umin32(t4[0], t4[2]); t2[1] = umin32(t4[1], t4[3]);
  return umin32(t2[0], t2[1]);
}

__device__ __forceinline__ int find_idx16(const unsigned* v, unsigned ws) {
  unsigned mbits = 0;
  #pragma unroll
  for (int s = 0; s < 16; ++s) mbits |= (v[s] == ws ? 1u : 0u) << s;
  unsigned long long bal = __ballot(mbits != 0);
  int fl = __ffsll(bal) - 1;
  int slot = __ffs(__builtin_amdgcn_readlane((int)mbits, fl)) - 1;
  return fl * 16 + slot;
}

// One Prim step: consume C (or M if useM), spec-load predicted next row into X.
#define PRIM_ITER(kk, C0, C1, C2, C3, X0, X1, X2, X3)                            \
  {                                                                              \
    unsigned ws_a = wave_min_u32(local_min16(mw));   /* frontier argmin */       \
    int ga = find_idx16(mw, ws_a);                                               \
    {                                                 /* speculative prefetch */ \
      const float4* rp = (const float4*)(Db + (size_t)ga * N);                   \
      X0 = rp[lane * 4];     X1 = rp[lane * 4 + 1];                              \
      X2 = rp[lane * 4 + 2]; X3 = rp[lane * 4 + 3];                              \
    }                                                                            \
    __builtin_amdgcn_sched_barrier(0);                /* keep loads issued here */\
    float4 c0 = useM ? m0 : C0; float4 c1 = useM ? m1 : C1;                      \
    float4 c2 = useM ? m2 : C2; float4 c3 = useM ? m3 : C3;                      \
    unsigned rv[16];                                                             \
    rv[0]=__float_as_uint(c0.x);  rv[1]=__float_as_uint(c0.y);                   \
    rv[2]=__float_as_uint(c0.z);  rv[3]=__float_as_uint(c0.w);                   \
    rv[4]=__float_as_uint(c1.x);  rv[5]=__float_as_uint(c1.y);                   \
    rv[6]=__float_as_uint(c1.z);  rv[7]=__float_as_uint(c1.w);                   \
    rv[8]=__float_as_uint(c2.x);  rv[9]=__float_as_uint(c2.y);                   \
    rv[10]=__float_as_uint(c2.z); rv[11]=__float_as_uint(c2.w);                  \
    rv[12]=__float_as_uint(c3.x); rv[13]=__float_as_uint(c3.y);                  \
    rv[14]=__float_as_uint(c3.z); rv[15]=__float_as_uint(c3.w);                  \
    unsigned rvm[16];                                                            \
    _Pragma("unroll")                                                            \
    for (int s = 0; s < 16; ++s) rvm[s] = rv[s] | rmask[s];                      \
    unsigned ws_r = wave_min_u32(local_min16(rvm));   /* weight only */          \
    unsigned w; int nj; bool miss;                                               \
    if (ws_a < ws_r)      { w = ws_a; nj = ga; miss = false; }                   \
    else if (ws_r < ws_a) { w = ws_r; nj = find_idx16(rvm, ws_r); miss = true; } \
    else { w = ws_a; int nr = find_idx16(rvm, ws_r);                             \
           nj = ga < nr ? ga : nr; miss = (nj != ga); }                          \
    if (miss) {                                       /* rare uniform branch */  \
      const float4* rp = (const float4*)(Db + (size_t)nj * N);                   \
      m0 = rp[lane * 4];     m1 = rp[lane * 4 + 1];                              \
      m2 = rp[lane * 4 + 2]; m3 = rp[lane * 4 + 3];                              \
    }                                                                            \
    useM = miss;                                                                 \
    _Pragma("unroll")                                                            \
    for (int s = 0; s < 16; ++s) {                                               \
      bool upd = rv[s] < mind[s];                     /* strict <, matches ref */\
      if (upd) { par[jbase + s] = cj; mind[s] = rv[s]; }                         \
      mw[s] = umin32(mw[s], rvm[s]);                                             \
    }                                                                            \
    if (lane == (nj >> 4)) { rmask[nj & 15] = ~0u; mw[nj & 15] = ~0u; }          \
    if (lane == 0) { epb[kk] = par[nj]; evb[kk] = nj; ewb[kk] = __uint_as_float(w); } \
    cj = nj;                                                                     \
  }

__global__ __launch_bounds__(64, 1) void prim_kernel(const float* __restrict__ dist,
    int* __restrict__ ep, int* __restrict__ ev, float* __restrict__ ewt) {
  __shared__ int par[N];
  const int b = blockIdx.x, lane = threadIdx.x;      // 64 threads
  const float* Db = dist + (size_t)b * N * N;
  const int jbase = lane * 16;
  int* epb = ep + b * NE;
  int* evb = ev + b * NE;
  float* ewb = ewt + b * NE;

  #pragma unroll
  for (int u = 0; u < 16; ++u) par[u * 64 + lane] = 0;

  unsigned mind[16], mw[16], rmask[16];
  {
    const float4* rp = (const float4*)Db;            // row 0
    #pragma unroll
    for (int u = 0; u < 4; ++u) {
      float4 v = rp[lane * 4 + u];
      mind[4*u+0] = __float_as_uint(v.x); mind[4*u+1] = __float_as_uint(v.y);
      mind[4*u+2] = __float_as_uint(v.z); mind[4*u+3] = __float_as_uint(v.w);
    }
  }
  #pragma unroll
  for (int s = 0; s < 16; ++s) { rmask[s] = 0u; mw[s] = mind[s]; }
  if (lane == 0) { rmask[0] = ~0u; mw[0] = ~0u; }    // node 0 in tree

  unsigned ws0 = wave_min_u32(local_min16(mw));
  int cj = find_idx16(mw, ws0);
  if (lane == 0) { epb[0] = 0; evb[0] = cj; ewb[0] = __uint_as_float(ws0); }
  if (lane == (cj >> 4)) { rmask[cj & 15] = ~0u; mw[cj & 15] = ~0u; }

  float4 a0, a1, a2, a3, b0, b1, b2, b3, m0, m1, m2, m3;
  {
    const float4* rp = (const float4*)(Db + (size_t)cj * N);
    a0 = rp[lane * 4]; a1 = rp[lane * 4 + 1]; a2 = rp[lane * 4 + 2]; a3 = rp[lane * 4 + 3];
  }
  m0 = a0; m1 = a1; m2 = a2; m3 = a3;                // init M (no pending loads)
  bool useM = false;

  for (int k = 1; k + 1 < NE; k += 2) {              // k = 1..1022, 511 pairs
    PRIM_ITER(k,     a0, a1, a2, a3, b0, b1, b2, b3);
    PRIM_ITER(k + 1, b0, b1, b2, b3, a0, a1, a2, a3);
  }
}

// ---------------- adjacency + deg^-1/2 (deterministic, no atomics) --------------
__global__ void adj_kernel(const int* __restrict__ ep, const int* __restrict__ ev,
    const float* __restrict__ ewt, int* __restrict__ adjI, float* __restrict__ adjW,
    int* __restrict__ cnt, float* __restrict__ dinv) {
  int i = blockIdx.x * 256 + threadIdx.x;
  int b = i >> 10, loc = i & 1023;
  const int* epb = ep + b * NE;
  const int* evb = ev + b * NE;
  const float* ewb = ewt + b * NE;
  int c = 0; float wsum = 0.0f;
  for (int k = 0; k < NE; ++k) {
    int p = epb[k], v = evb[k];
    if (p == loc || v == loc) {
      float w = ewb[k];
      wsum += w;
      int nb = (p == loc) ? v : p;
      if (c < CAP) { adjI[i * CAP + c] = (b << 10) + nb; adjW[i * CAP + c] = w; }
      ++c;
    }
  }
  cnt[i]  = c < CAP ? c : CAP;
  dinv[i] = 1.0f / sqrtf(wsum + 1.0f);
}

// ---------------- SSG propagation: h = alpha*x + (1-alpha)*A_hat x --------------
template <int HH>
__global__ void prop_kernel(const float* __restrict__ x, const int* __restrict__ adjI,
    const float* __restrict__ adjW, const int* __restrict__ cnt,
    const float* __restrict__ dinv, float* __restrict__ h) {
  constexpr int U = HH / 256;
  int wave = threadIdx.x >> 6, lane = threadIdx.x & 63;
  int i = blockIdx.x * 4 + wave;
  float dv = dinv[i];
  int c = cnt[i];
  float selfc = ALPHA + (1.0f - ALPHA) * dv * dv;
  float4 acc[U];
  const float* xi = x + (size_t)i * HH + lane * 4;
  #pragma unroll
  for (int u = 0; u < U; ++u) {
    float4 v = *(const float4*)(xi + u * 256);
    acc[u].x = selfc * v.x; acc[u].y = selfc * v.y;
    acc[u].z = selfc * v.z; acc[u].w = selfc * v.w;
  }
  for (int e = 0; e < c; ++e) {
    int j   = adjI[i * CAP + e];
    float w = adjW[i * CAP + e];
    float coef = (1.0f - ALPHA) * dv * (w * dinv[j]);
    const float* xj = x + (size_t)j * HH + lane * 4;
    #pragma unroll
    for (int u = 0; u < U; ++u) {
      float4 v = *(const float4*)(xj + u * 256);
      acc[u].x += coef * v.x; acc[u].y += coef * v.y;
      acc[u].z += coef * v.z; acc[u].w += coef * v.w;
    }
  }
  float* ho = h + (size_t)i * HH + lane * 4;
  #pragma unroll
  for (int u = 0; u < U; ++u) *(float4*)(ho + u * 256) = acc[u];
}

// ---------------- fused GEMM + bias + tanh: 128x128 tile, 8x8 per thread --------
template <int K>
__global__ __launch_bounds__(256) void gemm_tanh_kernel(const float* __restrict__ A,
    const float* __restrict__ W, const float* __restrict__ bias, float* __restrict__ C) {
  __shared__ float As[16][132], Bs[16][132];
  const int m0 = blockIdx.x * 128, n0 = blockIdx.y * 128;
  const int t = threadIdx.x, tx = t & 15, ty = t >> 4;
  float acc[8][8] = {};
  for (int kc = 0; kc < K; kc += 16) {
    #pragma unroll
    for (int u = 0; u < 2; ++u) {
      int q = t + u * 256;
      int row = q >> 2, kf = (q & 3) * 4;
      float4 a = *(const float4*)(A + (size_t)(m0 + row) * K + kc + kf);
      As[kf + 0][row] = a.x; As[kf + 1][row] = a.y;
      As[kf + 2][row] = a.z; As[kf + 3][row] = a.w;
      int rowB = q >> 5, cf = (q & 31) * 4;
      *(float4*)&Bs[rowB][cf] = *(const float4*)(W + (size_t)(kc + rowB) * H2 + n0 + cf);
    }
    __syncthreads();
    #pragma unroll
    for (int kk = 0; kk < 16; ++kk) {
      float4 a0 = *(const float4*)&As[kk][ty * 4];
      float4 a1 = *(const float4*)&As[kk][64 + ty * 4];
      float4 b0 = *(const float4*)&Bs[kk][tx * 4];
      float4 b1 = *(const float4*)&Bs[kk][64 + tx * 4];
      float ar[8] = {a0.x,a0.y,a0.z,a0.w,a1.x,a1.y,a1.z,a1.w};
      float br[8] = {b0.x,b0.y,b0.z,b0.w,b1.x,b1.y,b1.z,b1.w};
      #pragma unroll
      for (int r = 0; r < 8; ++r)
        #pragma unroll
        for (int c = 0; c < 8; ++c) acc[r][c] += ar[r] * br[c];
    }
    __syncthreads();
  }
  float4 bi0 = *(const float4*)(bias + n0 + tx * 4);
  float4 bi1 = *(const float4*)(bias + n0 + 64 + tx * 4);
  float bb[8] = {bi0.x,bi0.y,bi0.z,bi0.w,bi1.x,bi1.y,bi1.z,bi1.w};
  #pragma unroll
  for (int r = 0; r < 8; ++r) {
    int m = m0 + (r < 4 ? ty * 4 + r : 64 + ty * 4 + r - 4);
    float o[8];
    #pragma unroll
    for (int c = 0; c < 8; ++c) o[c] = tanhf(acc[r][c] + bb[c]);
    float* dst = C + (size_t)m * H2 + n0;
    *(float4*)(dst + tx * 4)      = make_float4(o[0], o[1], o[2], o[3]);
    *(float4*)(dst + 64 + tx * 4) = make_float4(o[4], o[5], o[6], o[7]);
  }
}

// ---------------- mean pool over N nodes per graph ------------------------------
__global__ void pool_kernel(const float* __restrict__ x, float* __restrict__ pooled) {
  int b = blockIdx.x;
  int c = blockIdx.y * 256 + threadIdx.x;
  const float* xb = x + ((size_t)b << 10) * H2 + c;
  float s = 0.0f;
  for (int i = 0; i < N; ++i) s += xb[(size_t)i * H2];
  pooled[b * H2 + c] = s * (1.0f / N);
}

// ---------------- dense head: tanh(pooled@Wd+bd) @ Wo + bo ----------------------
__global__ void head_kernel(const float* __restrict__ pooled, const float* __restrict__ Wd,
    const float* __restrict__ bd, const float* __restrict__ Wo, const float* __restrict__ bo,
    float* __restrict__ out) {
  __shared__ float sp[512], sh[256];
  int b = blockIdx.x, t = threadIdx.x;
  sp[t] = pooled[b * H2 + t];
  sp[t + 256] = pooled[b * H2 + t + 256];
  __syncthreads();
  float acc = bd[t];
  for (int c2 = 0; c2 < 512; ++c2) acc += sp[c2] * Wd[c2 * 256 + t];
  sh[t] = tanhf(acc);
  __syncthreads();
  if (t < 8) {
    float o = bo[t];
    for (int j = 0; j < 256; ++j) o += sh[j] * Wo[j * 8 + t];
    out[b * 8 + t] = o;
  }
}

}  // namespace

extern "C" void kernel_launch(void* const* d_in, const int* in_sizes, int n_in,
                              void* d_out, int out_size, void* d_ws, size_t ws_size,
                              hipStream_t stream) {
  const float* feat = (const float*)d_in[0];
  const float* W1 = (const float*)d_in[1];
  const float* b1 = (const float*)d_in[2];
  const float* W2 = (const float*)d_in[3];
  const float* b2 = (const float*)d_in[4];
  const float* W3 = (const float*)d_in[5];
  const float* b3 = (const float*)d_in[6];
  const float* Wd = (const float*)d_in[7];
  const float* bd = (const float*)d_in[8];
  const float* Wo = (const float*)d_in[9];
  const float* bo = (const float*)d_in[10];
  float* out = (float*)d_out;
  char* ws = (char*)d_ws;

  float* dist = (float*)(ws);
  float* xcur = (float*)(ws);                        // reuses dist after prim
  float* hbuf = (float*)(ws + ((size_t)64 << 20));
  char* misc  = ws + ((size_t)96 << 20);
  int*   ep     = (int*)(misc);
  int*   ev     = (int*)(misc + 65536);
  float* ewt    = (float*)(misc + 131072);
  int*   cnt    = (int*)(misc + 196608);
  float* dinv   = (float*)(misc + 262144);
  int*   adjI   = (int*)(misc + 327680);
  float* adjW   = (float*)(misc + 327680 + 2097152);
  float* n2     = (float*)(misc + 327680 + 2 * 2097152);
  float* pooled = (float*)(misc + 327680 + 2 * 2097152 + 65536);

  n2_kernel<<<NT / 4, 256, 0, stream>>>(feat, n2);
  dist_kernel<<<dim3(8, 8, 16), 256, 0, stream>>>(feat, n2, dist);
  prim_kernel<<<B, 64, 0, stream>>>(dist, ep, ev, ewt);
  adj_kernel<<<NT / 256, 256, 0, stream>>>(ep, ev, ewt, adjI, adjW, cnt, dinv);

  prop_kernel<256><<<NT / 4, 256, 0, stream>>>(feat, adjI, adjW, cnt, dinv, hbuf);
  gemm_tanh_kernel<256><<<dim3(NT / 128, 4), 256, 0, stream>>>(hbuf, W1, b1, xcur);
  prop_kernel<512><<<NT / 4, 256, 0, stream>>>(xcur, adjI, adjW, cnt, dinv, hbuf);
  gemm_tanh_kernel<512><<<dim3(NT / 128, 4), 256, 0, stream>>>(hbuf, W2, b2, xcur);
  prop_kernel<512><<<NT / 4, 256, 0, stream>>>(xcur, adjI, adjW, cnt, dinv, hbuf);
  gemm_tanh_kernel<512><<<dim3(NT / 128, 4), 256, 0, stream>>>(hbuf, W3, b3, xcur);

  pool_kernel<<<dim3(B, H2 / 256), 256, 0, stream>>>(xcur, pooled);
  head_kernel<<<B, 256, 0, stream>>>(pooled, Wd, bd, Wo, bo, out);
}

// Round 6
// 1612.199 us; speedup vs baseline: 1.2837x; 1.0234x over previous
//
#include <hip/hip_runtime.h>
#include <math.h>

namespace {

constexpr float ALPHA = 0.3f;
constexpr int B  = 16;
constexpr int N  = 1024;
constexpr int H  = 256;
constexpr int H2 = 512;
constexpr int NT = B * N;        // 16384 total nodes
constexpr int NE = N - 1;        // 1023 MST edges per batch
constexpr int CAP = 32;          // adjacency capacity per node (MST degree << 32)

__device__ __forceinline__ unsigned umin32(unsigned a, unsigned b) { return a < b ? a : b; }

// ---------------- row squared-norms: n2[row] = sum_k x[row][k]^2 ----------------
__global__ void n2_kernel(const float* __restrict__ x, float* __restrict__ n2) {
  int wave = threadIdx.x >> 6, lane = threadIdx.x & 63;
  int row  = blockIdx.x * 4 + wave;
  float4 v = *(const float4*)(x + (size_t)row * H + lane * 4);
  float s  = v.x * v.x + v.y * v.y + v.z * v.z + v.w * v.w;
  #pragma unroll
  for (int off = 32; off; off >>= 1) s += __shfl_xor(s, off);
  if (lane == 0) n2[row] = s;
}

// ---------------- distance matrix: 128x128 tile, 8x8 per thread -----------------
__global__ __launch_bounds__(256) void dist_kernel(const float* __restrict__ x,
    const float* __restrict__ n2, float* __restrict__ dist) {
  __shared__ float As[16][132], Bs[16][132];
  const int bb = blockIdx.z;
  const int i0 = blockIdx.y * 128, j0 = blockIdx.x * 128;
  const int t = threadIdx.x, tx = t & 15, ty = t >> 4;
  const float* xb = x + (size_t)bb * N * H;
  float acc[8][8] = {};
  for (int kc = 0; kc < H; kc += 16) {
    #pragma unroll
    for (int u = 0; u < 2; ++u) {
      int q = t + u * 256;
      int row = q >> 2, kf = (q & 3) * 4;          // 128 rows x 4 float4 of k
      float4 a = *(const float4*)(xb + (size_t)(i0 + row) * H + kc + kf);
      As[kf + 0][row] = a.x; As[kf + 1][row] = a.y;
      As[kf + 2][row] = a.z; As[kf + 3][row] = a.w;
      float4 bv = *(const float4*)(xb + (size_t)(j0 + row) * H + kc + kf);
      Bs[kf + 0][row] = bv.x; Bs[kf + 1][row] = bv.y;
      Bs[kf + 2][row] = bv.z; Bs[kf + 3][row] = bv.w;
    }
    __syncthreads();
    #pragma unroll
    for (int kk = 0; kk < 16; ++kk) {
      float4 a0 = *(const float4*)&As[kk][ty * 4];
      float4 a1 = *(const float4*)&As[kk][64 + ty * 4];
      float4 b0 = *(const float4*)&Bs[kk][tx * 4];
      float4 b1 = *(const float4*)&Bs[kk][64 + tx * 4];
      float ar[8] = {a0.x,a0.y,a0.z,a0.w,a1.x,a1.y,a1.z,a1.w};
      float br[8] = {b0.x,b0.y,b0.z,b0.w,b1.x,b1.y,b1.z,b1.w};
      #pragma unroll
      for (int r = 0; r < 8; ++r)
        #pragma unroll
        for (int c = 0; c < 8; ++c) acc[r][c] += ar[r] * br[c];
    }
    __syncthreads();
  }
  float n2i[8], n2j[8];
  #pragma unroll
  for (int r = 0; r < 8; ++r)
    n2i[r] = n2[bb * N + i0 + (r < 4 ? ty * 4 + r : 64 + ty * 4 + r - 4)];
  #pragma unroll
  for (int c = 0; c < 8; ++c)
    n2j[c] = n2[bb * N + j0 + (c < 4 ? tx * 4 + c : 64 + tx * 4 + c - 4)];
  #pragma unroll
  for (int r = 0; r < 8; ++r) {
    int mi = i0 + (r < 4 ? ty * 4 + r : 64 + ty * 4 + r - 4);
    float o[8];
    #pragma unroll
    for (int c = 0; c < 8; ++c) {
      float d2 = (n2i[r] + n2j[c]) - 2.0f * acc[r][c];
      o[c] = sqrtf(fmaxf(d2, 0.0f));
    }
    float* dst = dist + ((size_t)bb * N + mi) * N + j0;
    *(float4*)(dst + tx * 4)      = make_float4(o[0], o[1], o[2], o[3]);
    *(float4*)(dst + 64 + tx * 4) = make_float4(o[4], o[5], o[6], o[7]);
  }
}

// ---------------- Prim MST: asm loads + hand-counted vmcnt ----------------------
// 1 wave/batch. Node j: lane j>>4, slot j&15. Weights as u32 bits (non-neg fp32).
// ALL row loads are inline-asm (invisible to SIInsertWaitcnts); the ONLY vmem wait
// in the loop is our s_waitcnt vmcnt(4) at the consume, leaving the current spec
// load group in flight across iterations. Edge outputs buffered in LDS so no
// compiler stores (and no compiler waitcnts) exist inside the loop.
__device__ __forceinline__ unsigned wave_min_u32(unsigned x) {
  unsigned t;
  t = (unsigned)__builtin_amdgcn_update_dpp((int)x, (int)x, 0x111, 0xf, 0xf, false); x = umin32(x, t);
  t = (unsigned)__builtin_amdgcn_update_dpp((int)x, (int)x, 0x112, 0xf, 0xf, false); x = umin32(x, t);
  t = (unsigned)__builtin_amdgcn_update_dpp((int)x, (int)x, 0x114, 0xf, 0xf, false); x = umin32(x, t);
  t = (unsigned)__builtin_amdgcn_update_dpp((int)x, (int)x, 0x118, 0xf, 0xf, false); x = umin32(x, t);
  x = umin32(x, (unsigned)__shfl_xor((int)x, 16));
  x = umin32(x, (unsigned)__shfl_xor((int)x, 32));
  return (unsigned)__builtin_amdgcn_readlane((int)x, 63);
}

__device__ __forceinline__ unsigned local_min16(const unsigned* v) {
  unsigned t8[8], t4[4], t2[2];
  #pragma unroll
  for (int i = 0; i < 8; ++i) t8[i] = umin32(v[i], v[i + 8]);
  #pragma unroll
  for (int i = 0; i < 4; ++i) t4[i] = umin32(t8[i], t8[i + 4]);
  t2[0] = umin32(t4[0], t4[2]); t2[1] = umin32(t4[1], t4[3]);
  return umin32(t2[0], t2[1]);
}

__device__ __forceinline__ int find_idx16(const unsigned* v, unsigned ws) {
  unsigned mbits = 0;
  #pragma unroll
  for (int s = 0; s < 16; ++s) mbits |= (v[s] == ws ? 1u : 0u) << s;
  unsigned long long bal = __ballot(mbits != 0);
  int fl = __ffsll(bal) - 1;
  int slot = __ffs(__builtin_amdgcn_readlane((int)mbits, fl)) - 1;
  return fl * 16 + slot;
}

// 4x global_load_dwordx4, invisible to the compiler's waitcnt pass.
__device__ __forceinline__ void load_row_asm(const float* row, int lane,
    float4& x0, float4& x1, float4& x2, float4& x3) {
  const float* p = row + lane * 16;                 // 64B per lane, coalesced
  asm volatile(
      "global_load_dwordx4 %0, %4, off\n\t"
      "global_load_dwordx4 %1, %4, off offset:16\n\t"
      "global_load_dwordx4 %2, %4, off offset:32\n\t"
      "global_load_dwordx4 %3, %4, off offset:48"
      : "=&v"(x0), "=&v"(x1), "=&v"(x2), "=&v"(x3)
      : "v"(p) : "memory");
}

// One Prim step: consume C (or M if useM), spec-load predicted next row into X.
#define PRIM_ITER(kk, C0, C1, C2, C3, X0, X1, X2, X3)                            \
  {                                                                              \
    unsigned ws_a = wave_min_u32(local_min16(mw));   /* frontier argmin */       \
    int ga = find_idx16(mw, ws_a);                                               \
    load_row_asm(Db + (size_t)ga * N, lane, X0, X1, X2, X3);  /* speculative */  \
    asm volatile("s_waitcnt vmcnt(4)" ::: "memory"); /* prev group arrived */    \
    __builtin_amdgcn_sched_barrier(0);               /* no VALU hoists above */  \
    float4 c0 = useM ? m0 : C0; float4 c1 = useM ? m1 : C1;                      \
    float4 c2 = useM ? m2 : C2; float4 c3 = useM ? m3 : C3;                      \
    unsigned rv[16];                                                             \
    rv[0]=__float_as_uint(c0.x);  rv[1]=__float_as_uint(c0.y);                   \
    rv[2]=__float_as_uint(c0.z);  rv[3]=__float_as_uint(c0.w);                   \
    rv[4]=__float_as_uint(c1.x);  rv[5]=__float_as_uint(c1.y);                   \
    rv[6]=__float_as_uint(c1.z);  rv[7]=__float_as_uint(c1.w);                   \
    rv[8]=__float_as_uint(c2.x);  rv[9]=__float_as_uint(c2.y);                   \
    rv[10]=__float_as_uint(c2.z); rv[11]=__float_as_uint(c2.w);                  \
    rv[12]=__float_as_uint(c3.x); rv[13]=__float_as_uint(c3.y);                  \
    rv[14]=__float_as_uint(c3.z); rv[15]=__float_as_uint(c3.w);                  \
    unsigned rvm[16];                                                            \
    _Pragma("unroll")                                                            \
    for (int s = 0; s < 16; ++s) rvm[s] = rv[s] | rmask[s];                      \
    unsigned ws_r = wave_min_u32(local_min16(rvm));   /* weight only */          \
    unsigned w; int nj; bool miss;                                               \
    if (ws_a < ws_r)      { w = ws_a; nj = ga; miss = false; }                   \
    else if (ws_r < ws_a) { w = ws_r; nj = find_idx16(rvm, ws_r); miss = true; } \
    else { w = ws_a; int nr = find_idx16(rvm, ws_r);                             \
           nj = ga < nr ? ga : nr; miss = (nj != ga); }                          \
    if (miss) {                                       /* rare uniform branch */  \
      load_row_asm(Db + (size_t)nj * N, lane, m0, m1, m2, m3);                   \
    }                                                                            \
    useM = miss;                                                                 \
    _Pragma("unroll")                                                            \
    for (int s = 0; s < 16; ++s) {                                               \
      bool upd = rv[s] < mind[s];                     /* strict <, matches ref */\
      if (upd) { par[jbase + s] = cj; mind[s] = rv[s]; }                         \
      mw[s] = umin32(mw[s], rvm[s]);                                             \
    }                                                                            \
    if (lane == (nj >> 4)) { rmask[nj & 15] = ~0u; mw[nj & 15] = ~0u; }          \
    if (lane == 0) { epv[kk] = par[nj]; evv[kk] = nj; ews[kk] = __uint_as_float(w); } \
    cj = nj;                                                                     \
  }

__global__ __launch_bounds__(64, 1) void prim_kernel(const float* __restrict__ dist,
    int* __restrict__ ep, int* __restrict__ ev, float* __restrict__ ewt) {
  __shared__ int par[N];
  __shared__ int epv[NE];
  __shared__ int evv[NE];
  __shared__ float ews[NE];
  const int b = blockIdx.x, lane = threadIdx.x;      // 64 threads
  const float* Db = dist + (size_t)b * N * N;
  const int jbase = lane * 16;

  #pragma unroll
  for (int u = 0; u < 16; ++u) par[u * 64 + lane] = 0;

  unsigned mind[16], mw[16], rmask[16];
  {
    const float4* rp = (const float4*)Db;            // row 0 (plain loads, pre-loop)
    #pragma unroll
    for (int u = 0; u < 4; ++u) {
      float4 v = rp[lane * 4 + u];
      mind[4*u+0] = __float_as_uint(v.x); mind[4*u+1] = __float_as_uint(v.y);
      mind[4*u+2] = __float_as_uint(v.z); mind[4*u+3] = __float_as_uint(v.w);
    }
  }
  #pragma unroll
  for (int s = 0; s < 16; ++s) { rmask[s] = 0u; mw[s] = mind[s]; }
  if (lane == 0) { rmask[0] = ~0u; mw[0] = ~0u; }    // node 0 in tree

  unsigned ws0 = wave_min_u32(local_min16(mw));
  int cj = find_idx16(mw, ws0);
  if (lane == 0) { epv[0] = 0; evv[0] = cj; ews[0] = __uint_as_float(ws0); }
  if (lane == (cj >> 4)) { rmask[cj & 15] = ~0u; mw[cj & 15] = ~0u; }

  float4 a0, a1, a2, a3, b0, b1, b2, b3, m0, m1, m2, m3;
  load_row_asm(Db + (size_t)cj * N, lane, a0, a1, a2, a3);  // outstanding = 4
  m0 = m1 = m2 = m3 = make_float4(0.f, 0.f, 0.f, 0.f);      // M unused until a miss
  bool useM = false;

  for (int k = 1; k + 1 < NE; k += 2) {              // k = 1..1022, 511 pairs
    PRIM_ITER(k,     a0, a1, a2, a3, b0, b1, b2, b3);
    PRIM_ITER(k + 1, b0, b1, b2, b3, a0, a1, a2, a3);
  }

  // flush edge list LDS -> global (outside the loop; compiler waits are fine here)
  for (int e = lane; e < NE; e += 64) {
    ep[b * NE + e]  = epv[e];
    ev[b * NE + e]  = evv[e];
    ewt[b * NE + e] = ews[e];
  }
}

// ---------------- adjacency + deg^-1/2 (deterministic, no atomics) --------------
__global__ void adj_kernel(const int* __restrict__ ep, const int* __restrict__ ev,
    const float* __restrict__ ewt, int* __restrict__ adjI, float* __restrict__ adjW,
    int* __restrict__ cnt, float* __restrict__ dinv) {
  int i = blockIdx.x * 256 + threadIdx.x;
  int b = i >> 10, loc = i & 1023;
  const int* epb = ep + b * NE;
  const int* evb = ev + b * NE;
  const float* ewb = ewt + b * NE;
  int c = 0; float wsum = 0.0f;
  for (int k = 0; k < NE; ++k) {
    int p = epb[k], v = evb[k];
    if (p == loc || v == loc) {
      float w = ewb[k];
      wsum += w;
      int nb = (p == loc) ? v : p;
      if (c < CAP) { adjI[i * CAP + c] = (b << 10) + nb; adjW[i * CAP + c] = w; }
      ++c;
    }
  }
  cnt[i]  = c < CAP ? c : CAP;
  dinv[i] = 1.0f / sqrtf(wsum + 1.0f);
}

// ---------------- SSG propagation: h = alpha*x + (1-alpha)*A_hat x --------------
template <int HH>
__global__ void prop_kernel(const float* __restrict__ x, const int* __restrict__ adjI,
    const float* __restrict__ adjW, const int* __restrict__ cnt,
    const float* __restrict__ dinv, float* __restrict__ h) {
  constexpr int U = HH / 256;
  int wave = threadIdx.x >> 6, lane = threadIdx.x & 63;
  int i = blockIdx.x * 4 + wave;
  float dv = dinv[i];
  int c = cnt[i];
  float selfc = ALPHA + (1.0f - ALPHA) * dv * dv;
  float4 acc[U];
  const float* xi = x + (size_t)i * HH + lane * 4;
  #pragma unroll
  for (int u = 0; u < U; ++u) {
    float4 v = *(const float4*)(xi + u * 256);
    acc[u].x = selfc * v.x; acc[u].y = selfc * v.y;
    acc[u].z = selfc * v.z; acc[u].w = selfc * v.w;
  }
  for (int e = 0; e < c; ++e) {
    int j   = adjI[i * CAP + e];
    float w = adjW[i * CAP + e];
    float coef = (1.0f - ALPHA) * dv * (w * dinv[j]);
    const float* xj = x + (size_t)j * HH + lane * 4;
    #pragma unroll
    for (int u = 0; u < U; ++u) {
      float4 v = *(const float4*)(xj + u * 256);
      acc[u].x += coef * v.x; acc[u].y += coef * v.y;
      acc[u].z += coef * v.z; acc[u].w += coef * v.w;
    }
  }
  float* ho = h + (size_t)i * HH + lane * 4;
  #pragma unroll
  for (int u = 0; u < U; ++u) *(float4*)(ho + u * 256) = acc[u];
}

// ---------------- fused GEMM + bias + tanh: 128x128 tile, 8x8 per thread --------
template <int K>
__global__ __launch_bounds__(256) void gemm_tanh_kernel(const float* __restrict__ A,
    const float* __restrict__ W, const float* __restrict__ bias, float* __restrict__ C) {
  __shared__ float As[16][132], Bs[16][132];
  const int m0 = blockIdx.x * 128, n0 = blockIdx.y * 128;
  const int t = threadIdx.x, tx = t & 15, ty = t >> 4;
  float acc[8][8] = {};
  for (int kc = 0; kc < K; kc += 16) {
    #pragma unroll
    for (int u = 0; u < 2; ++u) {
      int q = t + u * 256;
      int row = q >> 2, kf = (q & 3) * 4;
      float4 a = *(const float4*)(A + (size_t)(m0 + row) * K + kc + kf);
      As[kf + 0][row] = a.x; As[kf + 1][row] = a.y;
      As[kf + 2][row] = a.z; As[kf + 3][row] = a.w;
      int rowB = q >> 5, cf = (q & 31) * 4;
      *(float4*)&Bs[rowB][cf] = *(const float4*)(W + (size_t)(kc + rowB) * H2 + n0 + cf);
    }
    __syncthreads();
    #pragma unroll
    for (int kk = 0; kk < 16; ++kk) {
      float4 a0 = *(const float4*)&As[kk][ty * 4];
      float4 a1 = *(const float4*)&As[kk][64 + ty * 4];
      float4 b0 = *(const float4*)&Bs[kk][tx * 4];
      float4 b1 = *(const float4*)&Bs[kk][64 + tx * 4];
      float ar[8] = {a0.x,a0.y,a0.z,a0.w,a1.x,a1.y,a1.z,a1.w};
      float br[8] = {b0.x,b0.y,b0.z,b0.w,b1.x,b1.y,b1.z,b1.w};
      #pragma unroll
      for (int r = 0; r < 8; ++r)
        #pragma unroll
        for (int c = 0; c < 8; ++c) acc[r][c] += ar[r] * br[c];
    }
    __syncthreads();
  }
  float4 bi0 = *(const float4*)(bias + n0 + tx * 4);
  float4 bi1 = *(const float4*)(bias + n0 + 64 + tx * 4);
  float bb[8] = {bi0.x,bi0.y,bi0.z,bi0.w,bi1.x,bi1.y,bi1.z,bi1.w};
  #pragma unroll
  for (int r = 0; r < 8; ++r) {
    int m = m0 + (r < 4 ? ty * 4 + r : 64 + ty * 4 + r - 4);
    float o[8];
    #pragma unroll
    for (int c = 0; c < 8; ++c) o[c] = tanhf(acc[r][c] + bb[c]);
    float* dst = C + (size_t)m * H2 + n0;
    *(float4*)(dst + tx * 4)      = make_float4(o[0], o[1], o[2], o[3]);
    *(float4*)(dst + 64 + tx * 4) = make_float4(o[4], o[5], o[6], o[7]);
  }
}

// ---------------- mean pool over N nodes per graph ------------------------------
__global__ void pool_kernel(const float* __restrict__ x, float* __restrict__ pooled) {
  int b = blockIdx.x;
  int c = blockIdx.y * 256 + threadIdx.x;
  const float* xb = x + ((size_t)b << 10) * H2 + c;
  float s = 0.0f;
  for (int i = 0; i < N; ++i) s += xb[(size_t)i * H2];
  pooled[b * H2 + c] = s * (1.0f / N);
}

// ---------------- dense head: tanh(pooled@Wd+bd) @ Wo + bo ----------------------
__global__ void head_kernel(const float* __restrict__ pooled, const float* __restrict__ Wd,
    const float* __restrict__ bd, const float* __restrict__ Wo, const float* __restrict__ bo,
    float* __restrict__ out) {
  __shared__ float sp[512], sh[256];
  int b = blockIdx.x, t = threadIdx.x;
  sp[t] = pooled[b * H2 + t];
  sp[t + 256] = pooled[b * H2 + t + 256];
  __syncthreads();
  float acc = bd[t];
  for (int c2 = 0; c2 < 512; ++c2) acc += sp[c2] * Wd[c2 * 256 + t];
  sh[t] = tanhf(acc);
  __syncthreads();
  if (t < 8) {
    float o = bo[t];
    for (int j = 0; j < 256; ++j) o += sh[j] * Wo[j * 8 + t];
    out[b * 8 + t] = o;
  }
}

}  // namespace

extern "C" void kernel_launch(void* const* d_in, const int* in_sizes, int n_in,
                              void* d_out, int out_size, void* d_ws, size_t ws_size,
                              hipStream_t stream) {
  const float* feat = (const float*)d_in[0];
  const float* W1 = (const float*)d_in[1];
  const float* b1 = (const float*)d_in[2];
  const float* W2 = (const float*)d_in[3];
  const float* b2 = (const float*)d_in[4];
  const float* W3 = (const float*)d_in[5];
  const float* b3 = (const float*)d_in[6];
  const float* Wd = (const float*)d_in[7];
  const float* bd = (const float*)d_in[8];
  const float* Wo = (const float*)d_in[9];
  const float* bo = (const float*)d_in[10];
  float* out = (float*)d_out;
  char* ws = (char*)d_ws;

  float* dist = (float*)(ws);
  float* xcur = (float*)(ws);                        // reuses dist after prim
  float* hbuf = (float*)(ws + ((size_t)64 << 20));
  char* misc  = ws + ((size_t)96 << 20);
  int*   ep     = (int*)(misc);
  int*   ev     = (int*)(misc + 65536);
  float* ewt    = (float*)(misc + 131072);
  int*   cnt    = (int*)(misc + 196608);
  float* dinv   = (float*)(misc + 262144);
  int*   adjI   = (int*)(misc + 327680);
  float* adjW   = (float*)(misc + 327680 + 2097152);
  float* n2     = (float*)(misc + 327680 + 2 * 2097152);
  float* pooled = (float*)(misc + 327680 + 2 * 2097152 + 65536);

  n2_kernel<<<NT / 4, 256, 0, stream>>>(feat, n2);
  dist_kernel<<<dim3(8, 8, 16), 256, 0, stream>>>(feat, n2, dist);
  prim_kernel<<<B, 64, 0, stream>>>(dist, ep, ev, ewt);
  adj_kernel<<<NT / 256, 256, 0, stream>>>(ep, ev, ewt, adjI, adjW, cnt, dinv);

  prop_kernel<256><<<NT / 4, 256, 0, stream>>>(feat, adjI, adjW, cnt, dinv, hbuf);
  gemm_tanh_kernel<256><<<dim3(NT / 128, 4), 256, 0, stream>>>(hbuf, W1, b1, xcur);
  prop_kernel<512><<<NT / 4, 256, 0, stream>>>(xcur, adjI, adjW, cnt, dinv, hbuf);
  gemm_tanh_kernel<512><<<dim3(NT / 128, 4), 256, 0, stream>>>(hbuf, W2, b2, xcur);
  prop_kernel<512><<<NT / 4, 256, 0, stream>>>(xcur, adjI, adjW, cnt, dinv, hbuf);
  gemm_tanh_kernel<512><<<dim3(NT / 128, 4), 256, 0, stream>>>(hbuf, W3, b3, xcur);

  pool_kernel<<<dim3(B, H2 / 256), 256, 0, stream>>>(xcur, pooled);
  head_kernel<<<B, 256, 0, stream>>>(pooled, Wd, bd, Wo, bo, out);
}

// Round 8
// 1299.642 us; speedup vs baseline: 1.5924x; 1.2405x over previous
//
#include <hip/hip_runtime.h>
#include <math.h>

namespace {

constexpr float ALPHA = 0.3f;
constexpr int B  = 16;
constexpr int N  = 1024;
constexpr int H  = 256;
constexpr int H2 = 512;
constexpr int NT = B * N;        // 16384 total nodes
constexpr int NE = N - 1;        // 1023 MST edges per batch
constexpr int CAP = 32;          // adjacency capacity per node (MST degree << 32)

__device__ __forceinline__ unsigned umin32(unsigned a, unsigned b) { return a < b ? a : b; }

// ---------------- row squared-norms: n2[row] = sum_k x[row][k]^2 ----------------
__global__ void n2_kernel(const float* __restrict__ x, float* __restrict__ n2) {
  int wave = threadIdx.x >> 6, lane = threadIdx.x & 63;
  int row  = blockIdx.x * 4 + wave;
  float4 v = *(const float4*)(x + (size_t)row * H + lane * 4);
  float s  = v.x * v.x + v.y * v.y + v.z * v.z + v.w * v.w;
  #pragma unroll
  for (int off = 32; off; off >>= 1) s += __shfl_xor(s, off);
  if (lane == 0) n2[row] = s;
}

// ---------------- distance matrix: 128x128 tile, 8x8 per thread -----------------
__global__ __launch_bounds__(256) void dist_kernel(const float* __restrict__ x,
    const float* __restrict__ n2, float* __restrict__ dist) {
  __shared__ float As[16][132], Bs[16][132];
  const int bb = blockIdx.z;
  const int i0 = blockIdx.y * 128, j0 = blockIdx.x * 128;
  const int t = threadIdx.x, tx = t & 15, ty = t >> 4;
  const float* xb = x + (size_t)bb * N * H;
  float acc[8][8] = {};
  for (int kc = 0; kc < H; kc += 16) {
    #pragma unroll
    for (int u = 0; u < 2; ++u) {
      int q = t + u * 256;
      int row = q >> 2, kf = (q & 3) * 4;          // 128 rows x 4 float4 of k
      float4 a = *(const float4*)(xb + (size_t)(i0 + row) * H + kc + kf);
      As[kf + 0][row] = a.x; As[kf + 1][row] = a.y;
      As[kf + 2][row] = a.z; As[kf + 3][row] = a.w;
      float4 bv = *(const float4*)(xb + (size_t)(j0 + row) * H + kc + kf);
      Bs[kf + 0][row] = bv.x; Bs[kf + 1][row] = bv.y;
      Bs[kf + 2][row] = bv.z; Bs[kf + 3][row] = bv.w;
    }
    __syncthreads();
    #pragma unroll
    for (int kk = 0; kk < 16; ++kk) {
      float4 a0 = *(const float4*)&As[kk][ty * 4];
      float4 a1 = *(const float4*)&As[kk][64 + ty * 4];
      float4 b0 = *(const float4*)&Bs[kk][tx * 4];
      float4 b1 = *(const float4*)&Bs[kk][64 + tx * 4];
      float ar[8] = {a0.x,a0.y,a0.z,a0.w,a1.x,a1.y,a1.z,a1.w};
      float br[8] = {b0.x,b0.y,b0.z,b0.w,b1.x,b1.y,b1.z,b1.w};
      #pragma unroll
      for (int r = 0; r < 8; ++r)
        #pragma unroll
        for (int c = 0; c < 8; ++c) acc[r][c] += ar[r] * br[c];
    }
    __syncthreads();
  }
  float n2i[8], n2j[8];
  #pragma unroll
  for (int r = 0; r < 8; ++r)
    n2i[r] = n2[bb * N + i0 + (r < 4 ? ty * 4 + r : 64 + ty * 4 + r - 4)];
  #pragma unroll
  for (int c = 0; c < 8; ++c)
    n2j[c] = n2[bb * N + j0 + (c < 4 ? tx * 4 + c : 64 + tx * 4 + c - 4)];
  #pragma unroll
  for (int r = 0; r < 8; ++r) {
    int mi = i0 + (r < 4 ? ty * 4 + r : 64 + ty * 4 + r - 4);
    float o[8];
    #pragma unroll
    for (int c = 0; c < 8; ++c) {
      float d2 = (n2i[r] + n2j[c]) - 2.0f * acc[r][c];
      o[c] = sqrtf(fmaxf(d2, 0.0f));
    }
    float* dst = dist + ((size_t)bb * N + mi) * N + j0;
    *(float4*)(dst + tx * 4)      = make_float4(o[0], o[1], o[2], o[3]);
    *(float4*)(dst + 64 + tx * 4) = make_float4(o[4], o[5], o[6], o[7]);
  }
}

// ---------------- Prim MST: 4 waves/batch, all-scalar state, no asm --------------
// Node j: thread j>>2, slot j&3. Per-thread SCALARS (no arrays -> no scratch):
// d0..d3 = mind, mw0..3 = selection values (in-tree == ~0u), rm0..3 = masks,
// pa0..3 = parents. Selection: 3-op local min -> DPP wave-min -> ballot lowest
// lane -> ffs lowest slot -> u64 key (w<<32|node, u64-min == jnp.argmin lowest-
// index tie-break) -> smin[wid] -> barrier -> 3 u64 mins -> barrier. Loads are
// plain (compiler inserts the vmcnt). Weights compared as u32 bits (non-neg fp).
__device__ __forceinline__ unsigned wave_min_u32(unsigned x) {
  unsigned t;
  t = (unsigned)__builtin_amdgcn_update_dpp((int)x, (int)x, 0x111, 0xf, 0xf, false); x = umin32(x, t);
  t = (unsigned)__builtin_amdgcn_update_dpp((int)x, (int)x, 0x112, 0xf, 0xf, false); x = umin32(x, t);
  t = (unsigned)__builtin_amdgcn_update_dpp((int)x, (int)x, 0x114, 0xf, 0xf, false); x = umin32(x, t);
  t = (unsigned)__builtin_amdgcn_update_dpp((int)x, (int)x, 0x118, 0xf, 0xf, false); x = umin32(x, t);
  x = umin32(x, (unsigned)__shfl_xor((int)x, 16));
  x = umin32(x, (unsigned)__shfl_xor((int)x, 32));
  return (unsigned)__builtin_amdgcn_readlane((int)x, 63);
}

struct Sel2 { unsigned w; int j; };

__device__ __forceinline__ Sel2 block_select(unsigned mw0, unsigned mw1,
    unsigned mw2, unsigned mw3, int wid, int lane, unsigned long long* smin) {
  unsigned lm = umin32(umin32(mw0, mw1), umin32(mw2, mw3));
  unsigned wm = wave_min_u32(lm);
  unsigned mb = (mw0 == wm ? 1u : 0u) | (mw1 == wm ? 2u : 0u) |
                (mw2 == wm ? 4u : 0u) | (mw3 == wm ? 8u : 0u);
  unsigned long long bal = __ballot(mb != 0);
  int fl = __ffsll(bal) - 1;                         // lowest matching lane
  int slot = __ffs((unsigned)__builtin_amdgcn_readlane((int)mb, fl)) - 1;
  int widx = (wid << 8) | (fl << 2) | slot;          // lowest node id in wave
  if (lane == 0)
    smin[wid] = ((unsigned long long)wm << 32) | (unsigned)widx;
  __syncthreads();                                   // writes visible
  unsigned long long k0 = smin[0], k1 = smin[1], k2 = smin[2], k3 = smin[3];
  unsigned long long ka = k0 < k1 ? k0 : k1;
  unsigned long long kb = k2 < k3 ? k2 : k3;
  unsigned long long kk = ka < kb ? ka : kb;
  __syncthreads();                                   // reads done before next write
  Sel2 r; r.w = (unsigned)(kk >> 32); r.j = (int)(unsigned)(kk & 0xFFFFFFFFu);
  return r;
}

__global__ __launch_bounds__(256, 1) void prim_kernel(const float* __restrict__ dist,
    int* __restrict__ ep, int* __restrict__ ev, float* __restrict__ ewt) {
  __shared__ unsigned long long smin[4];
  __shared__ int epv[NE];
  __shared__ int evv[NE];
  __shared__ float ews[NE];
  const int b = blockIdx.x;
  const int tid = threadIdx.x, wid = tid >> 6, lane = tid & 63;
  const float* Db = dist + (size_t)b * N * N;
  const int jbase = tid * 4;                          // this thread's 4 nodes

  unsigned d0, d1, d2, d3;                            // mind (scalars)
  {
    float4 v = *(const float4*)(Db + jbase);          // row 0
    d0 = __float_as_uint(v.x); d1 = __float_as_uint(v.y);
    d2 = __float_as_uint(v.z); d3 = __float_as_uint(v.w);
  }
  unsigned mw0 = d0, mw1 = d1, mw2 = d2, mw3 = d3;
  unsigned rm0 = 0, rm1 = 0, rm2 = 0, rm3 = 0;
  int pa0 = 0, pa1 = 0, pa2 = 0, pa3 = 0;
  if (tid == 0) { rm0 = ~0u; mw0 = ~0u; }             // node 0 in tree

  // ---- edge 0 ----
  Sel2 s0 = block_select(mw0, mw1, mw2, mw3, wid, lane, smin);
  int cj = s0.j;
  if ((cj >> 2) == tid) {
    int sl = cj & 3;
    int pv = pa0; if (sl == 1) pv = pa1; if (sl == 2) pv = pa2; if (sl == 3) pv = pa3;
    epv[0] = pv; evv[0] = cj; ews[0] = __uint_as_float(s0.w);
    if (sl == 0) { rm0 = ~0u; mw0 = ~0u; }
    if (sl == 1) { rm1 = ~0u; mw1 = ~0u; }
    if (sl == 2) { rm2 = ~0u; mw2 = ~0u; }
    if (sl == 3) { rm3 = ~0u; mw3 = ~0u; }
  }
  float4 xq = *(const float4*)(Db + (size_t)cj * N + jbase);  // plain load

  for (int k = 1; k < NE; ++k) {
    unsigned r0 = __float_as_uint(xq.x), r1 = __float_as_uint(xq.y);
    unsigned r2 = __float_as_uint(xq.z), r3 = __float_as_uint(xq.w);
    unsigned q0 = r0 | rm0, q1 = r1 | rm1, q2 = r2 | rm2, q3 = r3 | rm3;
    mw0 = umin32(mw0, q0); mw1 = umin32(mw1, q1);
    mw2 = umin32(mw2, q2); mw3 = umin32(mw3, q3);
    Sel2 se = block_select(mw0, mw1, mw2, mw3, wid, lane, smin);
    const int nj = se.j;
    float4 nxt = *(const float4*)(Db + (size_t)nj * N + jbase);  // next row
    // update mind/parents with row cj (strict <, matches reference)
    if (r0 < d0) { pa0 = cj; d0 = r0; }
    if (r1 < d1) { pa1 = cj; d1 = r1; }
    if (r2 < d2) { pa2 = cj; d2 = r2; }
    if (r3 < d3) { pa3 = cj; d3 = r3; }
    if ((nj >> 2) == tid) {                           // owner: emit + mask
      int sl = nj & 3;
      int pv = pa0; if (sl == 1) pv = pa1; if (sl == 2) pv = pa2; if (sl == 3) pv = pa3;
      epv[k] = pv; evv[k] = nj; ews[k] = __uint_as_float(se.w);
      if (sl == 0) { rm0 = ~0u; mw0 = ~0u; }
      if (sl == 1) { rm1 = ~0u; mw1 = ~0u; }
      if (sl == 2) { rm2 = ~0u; mw2 = ~0u; }
      if (sl == 3) { rm3 = ~0u; mw3 = ~0u; }
    }
    cj = nj; xq = nxt;
  }

  __syncthreads();                                    // epv/evv/ews visible
  for (int e = tid; e < NE; e += 256) {
    ep[b * NE + e]  = epv[e];
    ev[b * NE + e]  = evv[e];
    ewt[b * NE + e] = ews[e];
  }
}

// ---------------- adjacency + deg^-1/2 (deterministic, no atomics) --------------
__global__ void adj_kernel(const int* __restrict__ ep, const int* __restrict__ ev,
    const float* __restrict__ ewt, int* __restrict__ adjI, float* __restrict__ adjW,
    int* __restrict__ cnt, float* __restrict__ dinv) {
  int i = blockIdx.x * 256 + threadIdx.x;
  int b = i >> 10, loc = i & 1023;
  const int* epb = ep + b * NE;
  const int* evb = ev + b * NE;
  const float* ewb = ewt + b * NE;
  int c = 0; float wsum = 0.0f;
  for (int k = 0; k < NE; ++k) {
    int p = epb[k], v = evb[k];
    if (p == loc || v == loc) {
      float w = ewb[k];
      wsum += w;
      int nb = (p == loc) ? v : p;
      if (c < CAP) { adjI[i * CAP + c] = (b << 10) + nb; adjW[i * CAP + c] = w; }
      ++c;
    }
  }
  cnt[i]  = c < CAP ? c : CAP;
  dinv[i] = 1.0f / sqrtf(wsum + 1.0f);
}

// ---------------- SSG propagation: h = alpha*x + (1-alpha)*A_hat x --------------
template <int HH>
__global__ void prop_kernel(const float* __restrict__ x, const int* __restrict__ adjI,
    const float* __restrict__ adjW, const int* __restrict__ cnt,
    const float* __restrict__ dinv, float* __restrict__ h) {
  constexpr int U = HH / 256;
  int wave = threadIdx.x >> 6, lane = threadIdx.x & 63;
  int i = blockIdx.x * 4 + wave;
  float dv = dinv[i];
  int c = cnt[i];
  float selfc = ALPHA + (1.0f - ALPHA) * dv * dv;
  float4 acc[U];
  const float* xi = x + (size_t)i * HH + lane * 4;
  #pragma unroll
  for (int u = 0; u < U; ++u) {
    float4 v = *(const float4*)(xi + u * 256);
    acc[u].x = selfc * v.x; acc[u].y = selfc * v.y;
    acc[u].z = selfc * v.z; acc[u].w = selfc * v.w;
  }
  for (int e = 0; e < c; ++e) {
    int j   = adjI[i * CAP + e];
    float w = adjW[i * CAP + e];
    float coef = (1.0f - ALPHA) * dv * (w * dinv[j]);
    const float* xj = x + (size_t)j * HH + lane * 4;
    #pragma unroll
    for (int u = 0; u < U; ++u) {
      float4 v = *(const float4*)(xj + u * 256);
      acc[u].x += coef * v.x; acc[u].y += coef * v.y;
      acc[u].z += coef * v.z; acc[u].w += coef * v.w;
    }
  }
  float* ho = h + (size_t)i * HH + lane * 4;
  #pragma unroll
  for (int u = 0; u < U; ++u) *(float4*)(ho + u * 256) = acc[u];
}

// ---------------- fused GEMM + bias + tanh: 128x128 tile, 8x8 per thread --------
template <int K>
__global__ __launch_bounds__(256) void gemm_tanh_kernel(const float* __restrict__ A,
    const float* __restrict__ W, const float* __restrict__ bias, float* __restrict__ C) {
  __shared__ float As[16][132], Bs[16][132];
  const int m0 = blockIdx.x * 128, n0 = blockIdx.y * 128;
  const int t = threadIdx.x, tx = t & 15, ty = t >> 4;
  float acc[8][8] = {};
  for (int kc = 0; kc < K; kc += 16) {
    #pragma unroll
    for (int u = 0; u < 2; ++u) {
      int q = t + u * 256;
      int row = q >> 2, kf = (q & 3) * 4;
      float4 a = *(const float4*)(A + (size_t)(m0 + row) * K + kc + kf);
      As[kf + 0][row] = a.x; As[kf + 1][row] = a.y;
      As[kf + 2][row] = a.z; As[kf + 3][row] = a.w;
      int rowB = q >> 5, cf = (q & 31) * 4;
      *(float4*)&Bs[rowB][cf] = *(const float4*)(W + (size_t)(kc + rowB) * H2 + n0 + cf);
    }
    __syncthreads();
    #pragma unroll
    for (int kk = 0; kk < 16; ++kk) {
      float4 a0 = *(const float4*)&As[kk][ty * 4];
      float4 a1 = *(const float4*)&As[kk][64 + ty * 4];
      float4 b0 = *(const float4*)&Bs[kk][tx * 4];
      float4 b1 = *(const float4*)&Bs[kk][64 + tx * 4];
      float ar[8] = {a0.x,a0.y,a0.z,a0.w,a1.x,a1.y,a1.z,a1.w};
      float br[8] = {b0.x,b0.y,b0.z,b0.w,b1.x,b1.y,b1.z,b1.w};
      #pragma unroll
      for (int r = 0; r < 8; ++r)
        #pragma unroll
        for (int c = 0; c < 8; ++c) acc[r][c] += ar[r] * br[c];
    }
    __syncthreads();
  }
  float4 bi0 = *(const float4*)(bias + n0 + tx * 4);
  float4 bi1 = *(const float4*)(bias + n0 + 64 + tx * 4);
  float bb[8] = {bi0.x,bi0.y,bi0.z,bi0.w,bi1.x,bi1.y,bi1.z,bi1.w};
  #pragma unroll
  for (int r = 0; r < 8; ++r) {
    int m = m0 + (r < 4 ? ty * 4 + r : 64 + ty * 4 + r - 4);
    float o[8];
    #pragma unroll
    for (int c = 0; c < 8; ++c) o[c] = tanhf(acc[r][c] + bb[c]);
    float* dst = C + (size_t)m * H2 + n0;
    *(float4*)(dst + tx * 4)      = make_float4(o[0], o[1], o[2], o[3]);
    *(float4*)(dst + 64 + tx * 4) = make_float4(o[4], o[5], o[6], o[7]);
  }
}

// ---------------- mean pool over N nodes per graph ------------------------------
__global__ void pool_kernel(const float* __restrict__ x, float* __restrict__ pooled) {
  int b = blockIdx.x;
  int c = blockIdx.y * 256 + threadIdx.x;
  const float* xb = x + ((size_t)b << 10) * H2 + c;
  float s = 0.0f;
  for (int i = 0; i < N; ++i) s += xb[(size_t)i * H2];
  pooled[b * H2 + c] = s * (1.0f / N);
}

// ---------------- dense head: tanh(pooled@Wd+bd) @ Wo + bo ----------------------
__global__ void head_kernel(const float* __restrict__ pooled, const float* __restrict__ Wd,
    const float* __restrict__ bd, const float* __restrict__ Wo, const float* __restrict__ bo,
    float* __restrict__ out) {
  __shared__ float sp[512], sh[256];
  int b = blockIdx.x, t = threadIdx.x;
  sp[t] = pooled[b * H2 + t];
  sp[t + 256] = pooled[b * H2 + t + 256];
  __syncthreads();
  float acc = bd[t];
  for (int c2 = 0; c2 < 512; ++c2) acc += sp[c2] * Wd[c2 * 256 + t];
  sh[t] = tanhf(acc);
  __syncthreads();
  if (t < 8) {
    float o = bo[t];
    for (int j = 0; j < 256; ++j) o += sh[j] * Wo[j * 8 + t];
    out[b * 8 + t] = o;
  }
}

}  // namespace

extern "C" void kernel_launch(void* const* d_in, const int* in_sizes, int n_in,
                              void* d_out, int out_size, void* d_ws, size_t ws_size,
                              hipStream_t stream) {
  const float* feat = (const float*)d_in[0];
  const float* W1 = (const float*)d_in[1];
  const float* b1 = (const float*)d_in[2];
  const float* W2 = (const float*)d_in[3];
  const float* b2 = (const float*)d_in[4];
  const float* W3 = (const float*)d_in[5];
  const float* b3 = (const float*)d_in[6];
  const float* Wd = (const float*)d_in[7];
  const float* bd = (const float*)d_in[8];
  const float* Wo = (const float*)d_in[9];
  const float* bo = (const float*)d_in[10];
  float* out = (float*)d_out;
  char* ws = (char*)d_ws;

  float* dist = (float*)(ws);
  float* xcur = (float*)(ws);                        // reuses dist after prim
  float* hbuf = (float*)(ws + ((size_t)64 << 20));
  char* misc  = ws + ((size_t)96 << 20);
  int*   ep     = (int*)(misc);
  int*   ev     = (int*)(misc + 65536);
  float* ewt    = (float*)(misc + 131072);
  int*   cnt    = (int*)(misc + 196608);
  float* dinv   = (float*)(misc + 262144);
  int*   adjI   = (int*)(misc + 327680);
  float* adjW   = (float*)(misc + 327680 + 2097152);
  float* n2     = (float*)(misc + 327680 + 2 * 2097152);
  float* pooled = (float*)(misc + 327680 + 2 * 2097152 + 65536);

  n2_kernel<<<NT / 4, 256, 0, stream>>>(feat, n2);
  dist_kernel<<<dim3(8, 8, 16), 256, 0, stream>>>(feat, n2, dist);
  prim_kernel<<<B, 256, 0, stream>>>(dist, ep, ev, ewt);
  adj_kernel<<<NT / 256, 256, 0, stream>>>(ep, ev, ewt, adjI, adjW, cnt, dinv);

  prop_kernel<256><<<NT / 4, 256, 0, stream>>>(feat, adjI, adjW, cnt, dinv, hbuf);
  gemm_tanh_kernel<256><<<dim3(NT / 128, 4), 256, 0, stream>>>(hbuf, W1, b1, xcur);
  prop_kernel<512><<<NT / 4, 256, 0, stream>>>(xcur, adjI, adjW, cnt, dinv, hbuf);
  gemm_tanh_kernel<512><<<dim3(NT / 128, 4), 256, 0, stream>>>(hbuf, W2, b2, xcur);
  prop_kernel<512><<<NT / 4, 256, 0, stream>>>(xcur, adjI, adjW, cnt, dinv, hbuf);
  gemm_tanh_kernel<512><<<dim3(NT / 128, 4), 256, 0, stream>>>(hbuf, W3, b3, xcur);

  pool_kernel<<<dim3(B, H2 / 256), 256, 0, stream>>>(xcur, pooled);
  head_kernel<<<B, 256, 0, stream>>>(pooled, Wd, bd, Wo, bo, out);
}